// Round 1
// baseline (2450.409 us; speedup 1.0000x reference)
//
#include <hip/hip_runtime.h>
#include <math.h>

#define L_SEQ 8192
#define DM 1024
#define DI 2048
#define NH 32
#define HD 64
#define DS 128
#define CDIM 2304
#define DPROJ 4384
#define NCHUNK 16
#define CHUNK_L (L_SEQ / NCHUNK)

// ---------------------------------------------------------------------------
// C[m,n] = sum_k A[m*lda+k] * B[n*ldb+k]   (both row-major, K contiguous)
// 128x128 tile, BK=8, 256 threads, 8x8 per thread (2x2 split of 4-wide runs)
// ---------------------------------------------------------------------------
__global__ __launch_bounds__(256)
void gemm_tn(const float* __restrict__ A, int lda,
             const float* __restrict__ B, int ldb,
             float* __restrict__ C, int ldc,
             int M, int N, int K) {
  __shared__ float As[8][132];  // 132*4 = 528 bytes = 33*16 -> b128-aligned rows
  __shared__ float Bs[8][132];
  const int t = threadIdx.x;
  const int m0 = blockIdx.y * 128;
  const int n0 = blockIdx.x * 128;
  const int tx = t & 15;
  const int ty = t >> 4;

  float acc[8][8];
#pragma unroll
  for (int i = 0; i < 8; ++i)
#pragma unroll
    for (int j = 0; j < 8; ++j) acc[i][j] = 0.f;

  const int lrow = t >> 1;        // 0..127
  const int lkq  = (t & 1) * 4;   // 0 or 4

  for (int k0 = 0; k0 < K; k0 += 8) {
    float4 av = *(const float4*)(A + (size_t)(m0 + lrow) * lda + (k0 + lkq));
    float4 bv;
    int brow = n0 + lrow;
    if (brow < N) {
      bv = *(const float4*)(B + (size_t)brow * ldb + (k0 + lkq));
    } else {
      bv = make_float4(0.f, 0.f, 0.f, 0.f);
    }
    As[lkq + 0][lrow] = av.x;
    As[lkq + 1][lrow] = av.y;
    As[lkq + 2][lrow] = av.z;
    As[lkq + 3][lrow] = av.w;
    Bs[lkq + 0][lrow] = bv.x;
    Bs[lkq + 1][lrow] = bv.y;
    Bs[lkq + 2][lrow] = bv.z;
    Bs[lkq + 3][lrow] = bv.w;
    __syncthreads();
#pragma unroll
    for (int k = 0; k < 8; ++k) {
      float a[8], b[8];
#pragma unroll
      for (int i = 0; i < 4; ++i) {
        a[i]     = As[k][ty * 4 + i];
        a[i + 4] = As[k][64 + ty * 4 + i];
        b[i]     = Bs[k][tx * 4 + i];
        b[i + 4] = Bs[k][64 + tx * 4 + i];
      }
#pragma unroll
      for (int i = 0; i < 8; ++i)
#pragma unroll
        for (int j = 0; j < 8; ++j) acc[i][j] += a[i] * b[j];
    }
    __syncthreads();
  }
#pragma unroll
  for (int i = 0; i < 8; ++i) {
    int m = m0 + ty * 4 + (i & 3) + (i >> 2) * 64;
#pragma unroll
    for (int j = 0; j < 8; ++j) {
      int n = n0 + tx * 4 + (j & 3) + (j >> 2) * 64;
      if (n < N) C[(size_t)m * ldc + n] = acc[i][j];
    }
  }
}

// ---------------------------------------------------------------------------
// dt = softplus(zx[:, 4352+h] + dt_bias[h]); a = exp(-dt*exp(A_log[h]))
// ---------------------------------------------------------------------------
__global__ __launch_bounds__(256)
void dt_kernel(const float* __restrict__ zx, const float* __restrict__ dt_bias,
               const float* __restrict__ A_log, float* __restrict__ dt_out,
               float* __restrict__ a_out) {
  int idx = blockIdx.x * 256 + threadIdx.x;  // l*32 + h
  int l = idx >> 5, h = idx & 31;
  float v = zx[(size_t)l * DPROJ + (DI + CDIM) + h] + dt_bias[h];
  float d = (v > 20.f) ? v : log1pf(expf(v));
  dt_out[idx] = d;
  a_out[idx] = expf(-d * expf(A_log[h]));
}

// ---------------------------------------------------------------------------
// xbc[l,c] = silu( sum_{j=0..3} zx[l-1+j, 2048+c]*Wc[c,j] + bc[c] )
// (lax SAME, k=4 -> pad_low=1, pad_high=2)
// ---------------------------------------------------------------------------
__global__ __launch_bounds__(256)
void conv_silu_kernel(const float* __restrict__ zx, const float* __restrict__ Wc,
                      const float* __restrict__ bc, float* __restrict__ xbc) {
  int c = blockIdx.x * 256 + threadIdx.x;  // 0..2303
  int l = blockIdx.y;
  float s = bc[c];
#pragma unroll
  for (int j = 0; j < 4; ++j) {
    int ll = l - 1 + j;
    if (ll >= 0 && ll < L_SEQ) s += zx[(size_t)ll * DPROJ + DI + c] * Wc[c * 4 + j];
  }
  xbc[(size_t)l * CDIM + c] = s / (1.f + expf(-s));
}

// ---------------------------------------------------------------------------
// Hpart[chunk,h,n,p] = sum_{l in chunk} B[l,n] * (a[l,h]*dt[l,h]) * x_ssm[l,h,p]
// ---------------------------------------------------------------------------
__global__ __launch_bounds__(256)
void h_partial_kernel(const float* __restrict__ xbc, const float* __restrict__ dtb,
                      const float* __restrict__ aexp, float* __restrict__ Hpart) {
  int h = blockIdx.x;
  int chunk = blockIdx.y;
  int t = threadIdx.x;
  __shared__ float Bsh[4][DS];
  __shared__ float Vsh[4][HD];
  __shared__ float Ssh[4];
  float acc[32];
#pragma unroll
  for (int i = 0; i < 32; ++i) acc[i] = 0.f;
  int p = t & 63;
  int nq = t >> 6;  // 0..3
  int l0 = chunk * CHUNK_L;
  int sub = t >> 6;
  int lane = t & 63;
  for (int lb = 0; lb < CHUNK_L; lb += 4) {
    int l = l0 + lb + sub;
    const float* row = xbc + (size_t)l * CDIM;
    Bsh[sub][lane]      = row[DI + lane];
    Bsh[sub][64 + lane] = row[DI + 64 + lane];
    Vsh[sub][lane]      = row[h * HD + lane];
    if (lane == 0) Ssh[sub] = aexp[(size_t)l * NH + h] * dtb[(size_t)l * NH + h];
    __syncthreads();
#pragma unroll
    for (int s = 0; s < 4; ++s) {
      float v = Vsh[s][p] * Ssh[s];
#pragma unroll
      for (int i = 0; i < 32; ++i) acc[i] += Bsh[s][nq + i * 4] * v;
    }
    __syncthreads();
  }
  float* outp = Hpart + (size_t)(chunk * NH + h) * (DS * HD);
#pragma unroll
  for (int i = 0; i < 32; ++i) {
    int n = nq + i * 4;
    outp[n * HD + p] = acc[i];
  }
}

__global__ __launch_bounds__(256)
void h_reduce_kernel(const float* __restrict__ Hpart, float* __restrict__ H) {
  int idx = blockIdx.x * 256 + threadIdx.x;  // < 32*128*64
  float s = 0.f;
#pragma unroll
  for (int c = 0; c < NCHUNK; ++c) s += Hpart[(size_t)c * (NH * DS * HD) + idx];
  H[idx] = s;
}

// ---------------------------------------------------------------------------
// y[l, h*64+p] = sum_n C[l,n]*H[h,n,p] + D[h]*x_ssm[l,h,p]
// written IN-PLACE over xbc columns [0,2048) (stride CDIM); C cols untouched.
// ---------------------------------------------------------------------------
__global__ __launch_bounds__(256)
void y_kernel(float* __restrict__ xbc, const float* __restrict__ H,
              const float* __restrict__ D_param) {
  int h = blockIdx.y;
  int lt0 = blockIdx.x * 16;
  int t = threadIdx.x;
  __shared__ float Hs[DS][HD];       // 32 KB
  __shared__ float Cs[16][DS + 1];   // 8.25 KB
  const float* Hh = H + (size_t)h * DS * HD;
  for (int i = t; i < DS * HD; i += 256) Hs[i >> 6][i & 63] = Hh[i];
  for (int i = t; i < 16 * DS; i += 256) {
    int lr = i >> 7, cc = i & 127;
    Cs[lr][cc] = xbc[(size_t)(lt0 + lr) * CDIM + (DI + DS) + cc];
  }
  __syncthreads();
  int p = t & 63, lq = t >> 6;
  float Dh = D_param[h];
#pragma unroll
  for (int i = 0; i < 4; ++i) {
    int lr = lq * 4 + i;
    size_t off = (size_t)(lt0 + lr) * CDIM + h * HD + p;
    float s = 0.f;
#pragma unroll
    for (int n = 0; n < DS; ++n) s += Cs[lr][n] * Hs[n][p];
    float xs = xbc[off];
    xbc[off] = s + Dh * xs;
  }
}

// ---------------------------------------------------------------------------
// LayerNorm over 2048 + gate by z; write yz into zx cols [2048,4096)
// ---------------------------------------------------------------------------
__global__ __launch_bounds__(256)
void ln_mul_kernel(const float* __restrict__ ybuf, float* __restrict__ zx,
                   const float* __restrict__ ln_w, const float* __restrict__ ln_b) {
  int l = blockIdx.x;
  int t = threadIdx.x;
  const float* yrow = ybuf + (size_t)l * CDIM;
  float vals[8];
  float s = 0.f, sq = 0.f;
#pragma unroll
  for (int i = 0; i < 8; ++i) {
    float v = yrow[t + i * 256];
    vals[i] = v;
    s += v;
    sq += v * v;
  }
#pragma unroll
  for (int off = 32; off > 0; off >>= 1) {
    s += __shfl_down(s, off, 64);
    sq += __shfl_down(sq, off, 64);
  }
  __shared__ float red[10];
  int wave = t >> 6, lane = t & 63;
  if (lane == 0) { red[wave] = s; red[4 + wave] = sq; }
  __syncthreads();
  if (t == 0) {
    float S = red[0] + red[1] + red[2] + red[3];
    float SQ = red[4] + red[5] + red[6] + red[7];
    float mu = S / (float)DI;
    red[8] = mu;
    red[9] = rsqrtf(SQ / (float)DI - mu * mu + 1e-5f);
  }
  __syncthreads();
  float mu = red[8], rstd = red[9];
  float* zrow = zx + (size_t)l * DPROJ;
#pragma unroll
  for (int i = 0; i < 8; ++i) {
    int c = t + i * 256;
    float v = (vals[i] - mu) * rstd * ln_w[c] + ln_b[c];
    zrow[DI + c] = v * zrow[c];  // yz over dead xbc_raw cols
  }
}

// ---------------------------------------------------------------------------
extern "C" void kernel_launch(void* const* d_in, const int* in_sizes, int n_in,
                              void* d_out, int out_size, void* d_ws, size_t ws_size,
                              hipStream_t stream) {
  const float* x       = (const float*)d_in[0];
  const float* W_in    = (const float*)d_in[1];
  const float* W_conv  = (const float*)d_in[2];
  const float* b_conv  = (const float*)d_in[3];
  const float* dt_bias = (const float*)d_in[4];
  const float* A_log   = (const float*)d_in[5];
  const float* D_param = (const float*)d_in[6];
  const float* ln_w    = (const float*)d_in[7];
  const float* ln_b    = (const float*)d_in[8];
  const float* W_out   = (const float*)d_in[9];
  float* out = (float*)d_out;

  float* ws    = (float*)d_ws;
  float* zx    = ws;                                   // L*4384
  float* xbc   = zx + (size_t)L_SEQ * DPROJ;           // L*2304
  float* dtb   = xbc + (size_t)L_SEQ * CDIM;           // L*32
  float* aexp  = dtb + (size_t)L_SEQ * NH;             // L*32
  float* Hpart = aexp + (size_t)L_SEQ * NH;            // NCHUNK*32*128*64
  float* H     = Hpart + (size_t)NCHUNK * NH * DS * HD;  // 32*128*64
  // total ~239 MB of ws

  // 1) zx = x @ W_in^T   (M=8192, N=4384, K=1024)
  gemm_tn<<<dim3((DPROJ + 127) / 128, L_SEQ / 128), 256, 0, stream>>>(
      x, DM, W_in, DM, zx, DPROJ, L_SEQ, DPROJ, DM);

  // 2) dt / a
  dt_kernel<<<(L_SEQ * NH) / 256, 256, 0, stream>>>(zx, dt_bias, A_log, dtb, aexp);

  // 3) conv + silu
  conv_silu_kernel<<<dim3(CDIM / 256, L_SEQ), 256, 0, stream>>>(zx, W_conv, b_conv, xbc);

  // 4) H partials + reduce
  h_partial_kernel<<<dim3(NH, NCHUNK), 256, 0, stream>>>(xbc, dtb, aexp, Hpart);
  h_reduce_kernel<<<(NH * DS * HD) / 256, 256, 0, stream>>>(Hpart, H);

  // 5) y = C @ H + D*x_ssm (in-place into xbc cols [0,2048))
  y_kernel<<<dim3(L_SEQ / 16, NH), 256, 0, stream>>>(xbc, H, D_param);

  // 6) LN + z-gate -> yz into zx cols [2048,4096)
  ln_mul_kernel<<<L_SEQ, 256, 0, stream>>>(xbc, zx, ln_w, ln_b);

  // 7) out = yz @ W_out^T  (M=8192, N=1024, K=2048)
  gemm_tn<<<dim3(DM / 128, L_SEQ / 128), 256, 0, stream>>>(
      zx + DI, DPROJ, W_out, DI, out, DM, L_SEQ, DM, DI);
}

// Round 2
// 1245.454 us; speedup vs baseline: 1.9675x; 1.9675x over previous
//
#include <hip/hip_runtime.h>
#include <hip/hip_bf16.h>
#include <math.h>

#define L_SEQ 8192
#define DM 1024
#define DI 2048
#define NH 32
#define HD 64
#define DS 128
#define CDIM 2304
#define DPROJ 4384
#define NCHUNK 16
#define CHUNK_L (L_SEQ / NCHUNK)
#define NPAD_IN 4480  // 35 * 128, zero-padded rows of W_in for tile divisibility

typedef short bf16x8 __attribute__((ext_vector_type(8)));
typedef float floatx4 __attribute__((ext_vector_type(4)));
typedef unsigned short u16x4 __attribute__((ext_vector_type(4)));

#define AS1(p) ((const __attribute__((address_space(1))) void*)(p))
#define AS3(p) ((__attribute__((address_space(3))) void*)(p))

// ---------------------------------------------------------------------------
// bf16 MFMA GEMM (m97 structure): C[m,n] = sum_k A[m,k]*B[n,k]
// A: Mx K bf16 row-major (lda elems), B: N x K bf16 row-major (ldb elems).
// 128x128 tile, BK=32, 256 threads = 4 waves in 2x2, each wave 4x4 frags of
// 16x16x32. global_load_lds width=16 staging. N padded to tile; store guarded.
// ---------------------------------------------------------------------------
__global__ __launch_bounds__(256)
void gemm_bt_mfma(const unsigned short* __restrict__ A, int lda,
                  const unsigned short* __restrict__ B, int ldb,
                  float* __restrict__ C, int ldc,
                  int K, int Nstore) {
  __shared__ unsigned short Asm[128 * 32];  // 8 KB, row-major [m][k]
  __shared__ unsigned short Bsm[128 * 32];  // 8 KB, row-major [n][k]
  const int t = threadIdx.x;
  const int m0 = blockIdx.y * 128;
  const int n0 = blockIdx.x * 128;
  const int wave = t >> 6, lane = t & 63;
  const int wm = (wave & 1) * 64;
  const int wn = (wave >> 1) * 64;
  const int fr = lane & 15;     // fragment row/col within 16
  const int quad = lane >> 4;   // 0..3 -> k-offset quad*8 (inputs), row quad*4 (C/D)

  floatx4 acc[4][4];
#pragma unroll
  for (int i = 0; i < 4; ++i)
#pragma unroll
    for (int j = 0; j < 4; ++j) acc[i][j] = (floatx4){0.f, 0.f, 0.f, 0.f};

  for (int k0 = 0; k0 < K; k0 += 32) {
    // Stage 128x32 bf16 tiles of A and B: 2 issues of 256 lanes x 16 B each.
    // LDS dest = wave-uniform base + lane*16 (required by global_load_lds).
#pragma unroll
    for (int i = 0; i < 2; ++i) {
      int linear = i * 256 + t;          // 0..511
      int row = linear >> 2;             // 0..127
      int kq = (linear & 3) * 8;         // 0,8,16,24 (bf16 elems)
      const unsigned short* ga = A + (size_t)(m0 + row) * lda + (k0 + kq);
      const unsigned short* gb = B + (size_t)(n0 + row) * ldb + (k0 + kq);
      __builtin_amdgcn_global_load_lds(AS1(ga), AS3(&Asm[linear * 8]), 16, 0, 0);
      __builtin_amdgcn_global_load_lds(AS1(gb), AS3(&Bsm[linear * 8]), 16, 0, 0);
    }
    __syncthreads();

    bf16x8 af[4], bfr[4];
#pragma unroll
    for (int i = 0; i < 4; ++i) {
      af[i]  = *(const bf16x8*)&Asm[(wm + i * 16 + fr) * 32 + quad * 8];
      bfr[i] = *(const bf16x8*)&Bsm[(wn + i * 16 + fr) * 32 + quad * 8];
    }
#pragma unroll
    for (int mi = 0; mi < 4; ++mi)
#pragma unroll
      for (int ni = 0; ni < 4; ++ni)
        acc[mi][ni] = __builtin_amdgcn_mfma_f32_16x16x32_bf16(
            af[mi], bfr[ni], acc[mi][ni], 0, 0, 0);
    __syncthreads();
  }

  // Epilogue: C/D layout col = lane&15, row = (lane>>4)*4 + r  [m89-verified]
#pragma unroll
  for (int mi = 0; mi < 4; ++mi)
#pragma unroll
    for (int ni = 0; ni < 4; ++ni) {
      int col = n0 + wn + ni * 16 + fr;
      if (col < Nstore) {
        size_t base = (size_t)(m0 + wm + mi * 16 + quad * 4) * ldc + col;
#pragma unroll
        for (int r = 0; r < 4; ++r) C[base + (size_t)r * ldc] = acc[mi][ni][r];
      }
    }
}

// ---------------------------------------------------------------------------
// fp32 -> bf16 casts (4 elems/thread)
// ---------------------------------------------------------------------------
__global__ __launch_bounds__(256)
void cast_bf16_kernel(const float* __restrict__ in, unsigned short* __restrict__ out) {
  size_t i4 = ((size_t)blockIdx.x * 256 + threadIdx.x) * 4;
  float4 v = *(const float4*)(in + i4);
  u16x4 o;
  o.x = __bfloat16_as_ushort(__float2bfloat16(v.x));
  o.y = __bfloat16_as_ushort(__float2bfloat16(v.y));
  o.z = __bfloat16_as_ushort(__float2bfloat16(v.z));
  o.w = __bfloat16_as_ushort(__float2bfloat16(v.w));
  *(u16x4*)(out + i4) = o;
}

// W_in (4384x1024) -> bf16 padded to 4480 rows (pad rows = 0)
__global__ __launch_bounds__(256)
void cast_win_pad_kernel(const float* __restrict__ in, unsigned short* __restrict__ out) {
  size_t i4 = ((size_t)blockIdx.x * 256 + threadIdx.x) * 4;  // over 4480*1024
  int row = (int)(i4 >> 10);
  u16x4 o = (u16x4){0, 0, 0, 0};
  if (row < DPROJ) {
    float4 v = *(const float4*)(in + i4);
    o.x = __bfloat16_as_ushort(__float2bfloat16(v.x));
    o.y = __bfloat16_as_ushort(__float2bfloat16(v.y));
    o.z = __bfloat16_as_ushort(__float2bfloat16(v.z));
    o.w = __bfloat16_as_ushort(__float2bfloat16(v.w));
  }
  *(u16x4*)(out + i4) = o;
}

// ---------------------------------------------------------------------------
// dt = softplus(zx[:, 4352+h] + dt_bias[h]); a = exp(-dt*exp(A_log[h]))
// ---------------------------------------------------------------------------
__global__ __launch_bounds__(256)
void dt_kernel(const float* __restrict__ zx, const float* __restrict__ dt_bias,
               const float* __restrict__ A_log, float* __restrict__ dt_out,
               float* __restrict__ a_out) {
  int idx = blockIdx.x * 256 + threadIdx.x;  // l*32 + h
  int l = idx >> 5, h = idx & 31;
  float v = zx[(size_t)l * DPROJ + (DI + CDIM) + h] + dt_bias[h];
  float d = (v > 20.f) ? v : log1pf(expf(v));
  dt_out[idx] = d;
  a_out[idx] = expf(-d * expf(A_log[h]));
}

// ---------------------------------------------------------------------------
// xbc[l,c] = silu( sum_{j=0..3} zx[l-1+j, 2048+c]*Wc[c,j] + bc[c] )
// ---------------------------------------------------------------------------
__global__ __launch_bounds__(256)
void conv_silu_kernel(const float* __restrict__ zx, const float* __restrict__ Wc,
                      const float* __restrict__ bc, float* __restrict__ xbc) {
  int c = blockIdx.x * 256 + threadIdx.x;
  int l = blockIdx.y;
  float s = bc[c];
#pragma unroll
  for (int j = 0; j < 4; ++j) {
    int ll = l - 1 + j;
    if (ll >= 0 && ll < L_SEQ) s += zx[(size_t)ll * DPROJ + DI + c] * Wc[c * 4 + j];
  }
  xbc[(size_t)l * CDIM + c] = s / (1.f + expf(-s));
}

// ---------------------------------------------------------------------------
// Hpart[chunk,h,n,p] = sum_{l in chunk} B[l,n] * (a[l,h]*dt[l,h]) * x_ssm[l,h,p]
// ---------------------------------------------------------------------------
__global__ __launch_bounds__(256)
void h_partial_kernel(const float* __restrict__ xbc, const float* __restrict__ dtb,
                      const float* __restrict__ aexp, float* __restrict__ Hpart) {
  int h = blockIdx.x;
  int chunk = blockIdx.y;
  int t = threadIdx.x;
  __shared__ float Bsh[4][DS];
  __shared__ float Vsh[4][HD];
  __shared__ float Ssh[4];
  float acc[32];
#pragma unroll
  for (int i = 0; i < 32; ++i) acc[i] = 0.f;
  int p = t & 63;
  int nq = t >> 6;
  int l0 = chunk * CHUNK_L;
  int sub = t >> 6;
  int lane = t & 63;
  for (int lb = 0; lb < CHUNK_L; lb += 4) {
    int l = l0 + lb + sub;
    const float* row = xbc + (size_t)l * CDIM;
    Bsh[sub][lane]      = row[DI + lane];
    Bsh[sub][64 + lane] = row[DI + 64 + lane];
    Vsh[sub][lane]      = row[h * HD + lane];
    if (lane == 0) Ssh[sub] = aexp[(size_t)l * NH + h] * dtb[(size_t)l * NH + h];
    __syncthreads();
#pragma unroll
    for (int s = 0; s < 4; ++s) {
      float v = Vsh[s][p] * Ssh[s];
#pragma unroll
      for (int i = 0; i < 32; ++i) acc[i] += Bsh[s][nq + i * 4] * v;
    }
    __syncthreads();
  }
  float* outp = Hpart + (size_t)(chunk * NH + h) * (DS * HD);
#pragma unroll
  for (int i = 0; i < 32; ++i) {
    int n = nq + i * 4;
    outp[n * HD + p] = acc[i];
  }
}

__global__ __launch_bounds__(256)
void h_reduce_kernel(const float* __restrict__ Hpart, float* __restrict__ H) {
  int idx = blockIdx.x * 256 + threadIdx.x;
  float s = 0.f;
#pragma unroll
  for (int c = 0; c < NCHUNK; ++c) s += Hpart[(size_t)c * (NH * DS * HD) + idx];
  H[idx] = s;
}

// ---------------------------------------------------------------------------
// y[l, h*64+p] = sum_n C[l,n]*H[h,n,p] + D[h]*x_ssm[l,h,p]  (in-place in xbc)
// ---------------------------------------------------------------------------
__global__ __launch_bounds__(256)
void y_kernel(float* __restrict__ xbc, const float* __restrict__ H,
              const float* __restrict__ D_param) {
  int h = blockIdx.y;
  int lt0 = blockIdx.x * 16;
  int t = threadIdx.x;
  __shared__ float Hs[DS][HD];
  __shared__ float Cs[16][DS + 1];
  const float* Hh = H + (size_t)h * DS * HD;
  for (int i = t; i < DS * HD; i += 256) Hs[i >> 6][i & 63] = Hh[i];
  for (int i = t; i < 16 * DS; i += 256) {
    int lr = i >> 7, cc = i & 127;
    Cs[lr][cc] = xbc[(size_t)(lt0 + lr) * CDIM + (DI + DS) + cc];
  }
  __syncthreads();
  int p = t & 63, lq = t >> 6;
  float Dh = D_param[h];
#pragma unroll
  for (int i = 0; i < 4; ++i) {
    int lr = lq * 4 + i;
    size_t off = (size_t)(lt0 + lr) * CDIM + h * HD + p;
    float s = 0.f;
#pragma unroll
    for (int n = 0; n < DS; ++n) s += Cs[lr][n] * Hs[n][p];
    float xs = xbc[off];
    xbc[off] = s + Dh * xs;
  }
}

// ---------------------------------------------------------------------------
// LayerNorm over 2048 + z-gate; emit bf16 yz into zx cols [2048,3072) raw.
// ---------------------------------------------------------------------------
__global__ __launch_bounds__(256)
void ln_mul_kernel(const float* __restrict__ ybuf, float* __restrict__ zx,
                   const float* __restrict__ ln_w, const float* __restrict__ ln_b) {
  int l = blockIdx.x;
  int t = threadIdx.x;
  const float* yrow = ybuf + (size_t)l * CDIM;
  float vals[8];
  float s = 0.f, sq = 0.f;
#pragma unroll
  for (int i = 0; i < 8; ++i) {
    float v = yrow[t + i * 256];
    vals[i] = v;
    s += v;
    sq += v * v;
  }
#pragma unroll
  for (int off = 32; off > 0; off >>= 1) {
    s += __shfl_down(s, off, 64);
    sq += __shfl_down(sq, off, 64);
  }
  __shared__ float red[10];
  int wave = t >> 6, lane = t & 63;
  if (lane == 0) { red[wave] = s; red[4 + wave] = sq; }
  __syncthreads();
  if (t == 0) {
    float S = red[0] + red[1] + red[2] + red[3];
    float SQ = red[4] + red[5] + red[6] + red[7];
    float mu = S / (float)DI;
    red[8] = mu;
    red[9] = rsqrtf(SQ / (float)DI - mu * mu + 1e-5f);
  }
  __syncthreads();
  float mu = red[8], rstd = red[9];
  float* zrow = zx + (size_t)l * DPROJ;
  unsigned short* yzb = (unsigned short*)(zrow + DI);  // bf16 over dead cols
#pragma unroll
  for (int i = 0; i < 8; ++i) {
    int c = t + i * 256;
    float v = (vals[i] - mu) * rstd * ln_w[c] + ln_b[c];
    yzb[c] = __bfloat16_as_ushort(__float2bfloat16(v * zrow[c]));
  }
}

// ---------------------------------------------------------------------------
extern "C" void kernel_launch(void* const* d_in, const int* in_sizes, int n_in,
                              void* d_out, int out_size, void* d_ws, size_t ws_size,
                              hipStream_t stream) {
  const float* x       = (const float*)d_in[0];
  const float* W_in    = (const float*)d_in[1];
  const float* W_conv  = (const float*)d_in[2];
  const float* b_conv  = (const float*)d_in[3];
  const float* dt_bias = (const float*)d_in[4];
  const float* A_log   = (const float*)d_in[5];
  const float* D_param = (const float*)d_in[6];
  const float* ln_w    = (const float*)d_in[7];
  const float* ln_b    = (const float*)d_in[8];
  const float* W_out   = (const float*)d_in[9];
  float* out = (float*)d_out;

  float* ws    = (float*)d_ws;
  float* zx    = ws;                                   // L*4384 f32
  float* xbc   = zx + (size_t)L_SEQ * DPROJ;           // L*2304 f32
  float* dtb   = xbc + (size_t)L_SEQ * CDIM;           // L*32
  float* aexp  = dtb + (size_t)L_SEQ * NH;             // L*32
  float* bigbuf = aexp + (size_t)L_SEQ * NH;           // 4,194,304 f32 union:
  //   phase A: x_bf16 (8192x1024 bf16)   phase B: Hpart (16x32x128x64 f32)
  float* H     = bigbuf + (size_t)NCHUNK * NH * DS * HD;  // 32*128*64
  float* woutb_f = H + (size_t)NH * DS * HD;           // 1024*2048 bf16 = 1,048,576 f32

  unsigned short* x_bf16   = (unsigned short*)bigbuf;
  float*          Hpart    = bigbuf;
  unsigned short* win_bf16 = (unsigned short*)xbc;     // alias: xbc dead until conv
  unsigned short* wout_bf16 = (unsigned short*)woutb_f;

  // 0) casts
  cast_bf16_kernel<<<(L_SEQ * DM) / 1024, 256, 0, stream>>>(x, x_bf16);
  cast_win_pad_kernel<<<(NPAD_IN * DM) / 1024, 256, 0, stream>>>(W_in, win_bf16);
  cast_bf16_kernel<<<(DM * DI) / 1024, 256, 0, stream>>>(W_out, wout_bf16);

  // 1) zx = x @ W_in^T  (M=8192, N=4384->4480 pad, K=1024)
  gemm_bt_mfma<<<dim3(NPAD_IN / 128, L_SEQ / 128), 256, 0, stream>>>(
      x_bf16, DM, win_bf16, DM, zx, DPROJ, DM, DPROJ);

  // 2) dt / a
  dt_kernel<<<(L_SEQ * NH) / 256, 256, 0, stream>>>(zx, dt_bias, A_log, dtb, aexp);

  // 3) conv + silu (overwrites win_bf16 alias — dead)
  conv_silu_kernel<<<dim3(CDIM / 256, L_SEQ), 256, 0, stream>>>(zx, W_conv, b_conv, xbc);

  // 4) H partials (overwrites x_bf16 alias — dead) + reduce
  h_partial_kernel<<<dim3(NH, NCHUNK), 256, 0, stream>>>(xbc, dtb, aexp, Hpart);
  h_reduce_kernel<<<(NH * DS * HD) / 256, 256, 0, stream>>>(Hpart, H);

  // 5) y = C @ H + D*x_ssm (in-place into xbc cols [0,2048))
  y_kernel<<<dim3(L_SEQ / 16, NH), 256, 0, stream>>>(xbc, H, D_param);

  // 6) LN + z-gate -> bf16 yz into zx cols [2048,3072)
  ln_mul_kernel<<<L_SEQ, 256, 0, stream>>>(xbc, zx, ln_w, ln_b);

  // 7) out = yz @ W_out^T  (M=8192, N=1024, K=2048); A rows stride DPROJ*2 bf16
  gemm_bt_mfma<<<dim3(DM / 128, L_SEQ / 128), 256, 0, stream>>>(
      (unsigned short*)(zx + DI), DPROJ * 2, wout_bf16, DI, out, DM, DI, DM);
}

// Round 3
// 469.897 us; speedup vs baseline: 5.2148x; 2.6505x over previous
//
#include <hip/hip_runtime.h>
#include <hip/hip_bf16.h>
#include <math.h>

#define L_SEQ 8192
#define DM 1024
#define DI 2048
#define NH 32
#define HD 64
#define DS 128
#define CDIM 2304
#define DPROJ 4384
#define NPAD_IN 4480  // 35*128, zero-padded W_in rows
#define KSPLIT 16
#define OPROWS 2176   // 2048 Vs^T rows + 128 B^T rows

typedef short bf16x8 __attribute__((ext_vector_type(8)));
typedef float floatx4 __attribute__((ext_vector_type(4)));
typedef unsigned short u16x4 __attribute__((ext_vector_type(4)));

#define AS1(p) ((const __attribute__((address_space(1))) void*)(p))
#define AS3(p) ((__attribute__((address_space(3))) void*)(p))

__device__ __forceinline__ float bf2f(unsigned short u) {
  union { unsigned int i; float f; } c; c.i = ((unsigned int)u) << 16; return c.f;
}
__device__ __forceinline__ unsigned short f2bf(float f) {
  return __bfloat16_as_ushort(__float2bfloat16(f));
}

// ---------------------------------------------------------------------------
// bf16 MFMA GEMM: C[m,n] = sum_k A[m,k]*B[n,k]  (K contiguous both operands)
// 128x128 tile, BK=32, 4 waves (2x2), 4x4 frags of 16x16x32 each.
// MODE 0: f32 store with col<Nstore guard.
// MODE 1: bf16 store, fused epilogue acc + Dvec[col>>6]*bf16(xs[m*ldc+col]).
// MODE 2: split-K — blockIdx.z picks K-chunk & partial slice (f32, no guard).
// ---------------------------------------------------------------------------
template <int MODE>
__global__ __launch_bounds__(256)
void gemm_bt_mfma(const unsigned short* __restrict__ A, int lda,
                  const unsigned short* __restrict__ B, int ldb,
                  void* __restrict__ Cout, int ldc,
                  int Kfull, int Nstore,
                  const unsigned short* __restrict__ xs,
                  const float* __restrict__ Dvec) {
  __shared__ unsigned short Asm[128 * 32];
  __shared__ unsigned short Bsm[128 * 32];
  const int t = threadIdx.x;
  const int m0 = blockIdx.y * 128;
  const int n0 = blockIdx.x * 128;
  int kstart = 0, klen = Kfull;
  if (MODE == 2) { klen = Kfull / KSPLIT; kstart = blockIdx.z * klen; }
  const int wave = t >> 6, lane = t & 63;
  const int wm = (wave & 1) * 64;
  const int wn = (wave >> 1) * 64;
  const int fr = lane & 15;
  const int quad = lane >> 4;

  floatx4 acc[4][4];
#pragma unroll
  for (int i = 0; i < 4; ++i)
#pragma unroll
    for (int j = 0; j < 4; ++j) acc[i][j] = (floatx4){0.f, 0.f, 0.f, 0.f};

  for (int k0 = kstart; k0 < kstart + klen; k0 += 32) {
#pragma unroll
    for (int i = 0; i < 2; ++i) {
      int linear = i * 256 + t;          // 0..511
      int row = linear >> 2;             // 0..127
      int kq = (linear & 3) * 8;         // bf16 elem offset in K
      const unsigned short* ga = A + (size_t)(m0 + row) * lda + (k0 + kq);
      const unsigned short* gb = B + (size_t)(n0 + row) * ldb + (k0 + kq);
      __builtin_amdgcn_global_load_lds(AS1(ga), AS3(&Asm[linear * 8]), 16, 0, 0);
      __builtin_amdgcn_global_load_lds(AS1(gb), AS3(&Bsm[linear * 8]), 16, 0, 0);
    }
    __syncthreads();

    bf16x8 af[4], bfr[4];
#pragma unroll
    for (int i = 0; i < 4; ++i) {
      af[i]  = *(const bf16x8*)&Asm[(wm + i * 16 + fr) * 32 + quad * 8];
      bfr[i] = *(const bf16x8*)&Bsm[(wn + i * 16 + fr) * 32 + quad * 8];
    }
#pragma unroll
    for (int mi = 0; mi < 4; ++mi)
#pragma unroll
      for (int ni = 0; ni < 4; ++ni)
        acc[mi][ni] = __builtin_amdgcn_mfma_f32_16x16x32_bf16(
            af[mi], bfr[ni], acc[mi][ni], 0, 0, 0);
    __syncthreads();
  }

  // C/D layout: col = lane&15, row = (lane>>4)*4 + r  [m89-verified]
  if (MODE == 1) {
    unsigned short* C = (unsigned short*)Cout;
    float Dh = Dvec[(n0 + wn) >> 6];  // head uniform per wave (64-col span)
#pragma unroll
    for (int mi = 0; mi < 4; ++mi)
#pragma unroll
      for (int ni = 0; ni < 4; ++ni) {
        int col = n0 + wn + ni * 16 + fr;
        size_t base = (size_t)(m0 + wm + mi * 16 + quad * 4) * ldc + col;
#pragma unroll
        for (int r = 0; r < 4; ++r) {
          float v = acc[mi][ni][r] + Dh * bf2f(xs[base + (size_t)r * ldc]);
          C[base + (size_t)r * ldc] = f2bf(v);
        }
      }
  } else {
    float* C = (float*)Cout;
    if (MODE == 2) C += (size_t)blockIdx.z * DS * DI;
#pragma unroll
    for (int mi = 0; mi < 4; ++mi)
#pragma unroll
      for (int ni = 0; ni < 4; ++ni) {
        int col = n0 + wn + ni * 16 + fr;
        if (MODE == 2 || col < Nstore) {
          size_t base = (size_t)(m0 + wm + mi * 16 + quad * 4) * ldc + col;
#pragma unroll
          for (int r = 0; r < 4; ++r) C[base + (size_t)r * ldc] = acc[mi][ni][r];
        }
      }
  }
}

// ---------------------------------------------------------------------------
__global__ __launch_bounds__(256)
void cast_bf16_kernel(const float* __restrict__ in, unsigned short* __restrict__ out) {
  size_t i4 = ((size_t)blockIdx.x * 256 + threadIdx.x) * 4;
  float4 v = *(const float4*)(in + i4);
  u16x4 o;
  o.x = f2bf(v.x); o.y = f2bf(v.y); o.z = f2bf(v.z); o.w = f2bf(v.w);
  *(u16x4*)(out + i4) = o;
}

__global__ __launch_bounds__(256)
void cast_win_pad_kernel(const float* __restrict__ in, unsigned short* __restrict__ out) {
  size_t i4 = ((size_t)blockIdx.x * 256 + threadIdx.x) * 4;  // over 4480*1024
  int row = (int)(i4 >> 10);
  u16x4 o = (u16x4){0, 0, 0, 0};
  if (row < DPROJ) {
    float4 v = *(const float4*)(in + i4);
    o.x = f2bf(v.x); o.y = f2bf(v.y); o.z = f2bf(v.z); o.w = f2bf(v.w);
  }
  *(u16x4*)(out + i4) = o;
}

// ---------------------------------------------------------------------------
// s[l,h] = dt * exp(-dt*exp(A_log[h])),  dt = softplus(zx[l,4352+h]+dt_bias[h])
// ---------------------------------------------------------------------------
__global__ __launch_bounds__(256)
void dt_kernel(const float* __restrict__ zx, const float* __restrict__ dt_bias,
               const float* __restrict__ A_log, float* __restrict__ s_out) {
  int idx = blockIdx.x * 256 + threadIdx.x;  // l*32 + h
  int l = idx >> 5, h = idx & 31;
  float v = zx[(size_t)l * DPROJ + (DI + CDIM) + h] + dt_bias[h];
  float d = (v > 20.f) ? v : log1pf(expf(v));
  s_out[idx] = d * expf(-d * expf(A_log[h]));
}

// ---------------------------------------------------------------------------
// conv+silu -> compact bf16: xs (L x 2048), bmat (L x 128), cb (L x 128)
// ---------------------------------------------------------------------------
__global__ __launch_bounds__(256)
void conv_silu_kernel(const float* __restrict__ zx, const float* __restrict__ Wc,
                      const float* __restrict__ bc,
                      unsigned short* __restrict__ xs,
                      unsigned short* __restrict__ bmat,
                      unsigned short* __restrict__ cb) {
  int c = blockIdx.x * 256 + threadIdx.x;  // 0..2303
  int l = blockIdx.y;
  float s = bc[c];
#pragma unroll
  for (int j = 0; j < 4; ++j) {
    int ll = l - 1 + j;
    if (ll >= 0 && ll < L_SEQ) s += zx[(size_t)ll * DPROJ + DI + c] * Wc[c * 4 + j];
  }
  float v = s / (1.f + expf(-s));
  unsigned short b = f2bf(v);
  if (c < DI)            xs[(size_t)l * DI + c] = b;
  else if (c < DI + DS)  bmat[(size_t)l * DS + (c - DI)] = b;
  else                   cb[(size_t)l * DS + (c - DI - DS)] = b;
}

// ---------------------------------------------------------------------------
// OpT[r][l]: r<2048 -> s[l,r>>6]*xs[l,r]; r in [2048,2176) -> bmat[l,r-2048]
// ---------------------------------------------------------------------------
__global__ __launch_bounds__(256)
void transpose_pack_kernel(const unsigned short* __restrict__ xs,
                           const unsigned short* __restrict__ bmat,
                           const float* __restrict__ s,
                           unsigned short* __restrict__ OpT) {
  __shared__ float tile[64][65];
  const int r0 = blockIdx.x * 64;
  const int l0 = blockIdx.y * 64;
  const int t = threadIdx.x;
  const bool isB = (r0 >= DI);
#pragma unroll
  for (int i = 0; i < 16; ++i) {
    int idx = i * 256 + t;
    int ro = idx & 63;
    int lo = idx >> 6;
    int l = l0 + lo;
    float v;
    if (isB) v = bf2f(bmat[(size_t)l * DS + (r0 - DI + ro)]);
    else     v = bf2f(xs[(size_t)l * DI + r0 + ro]) * s[(size_t)l * NH + (r0 >> 6)];
    tile[ro][lo] = v;
  }
  __syncthreads();
#pragma unroll
  for (int j = 0; j < 4; ++j) {
    int linear = j * 1024 + t * 4;
    int rr = linear >> 6;
    int lc = linear & 63;
    u16x4 o;
    o.x = f2bf(tile[rr][lc + 0]);
    o.y = f2bf(tile[rr][lc + 1]);
    o.z = f2bf(tile[rr][lc + 2]);
    o.w = f2bf(tile[rr][lc + 3]);
    *(u16x4*)&OpT[(size_t)(r0 + rr) * L_SEQ + l0 + lc] = o;
  }
}

// ---------------------------------------------------------------------------
// Ht[p][n] = bf16( sum_z Ppart[z][n][p] )
// ---------------------------------------------------------------------------
__global__ __launch_bounds__(256)
void h_reduce_t_kernel(const float* __restrict__ P, unsigned short* __restrict__ Ht) {
  __shared__ float tile[32][65];
  const int bid = blockIdx.x;
  const int pt = bid & 31, ng = bid >> 5;
  const int t = threadIdx.x;
#pragma unroll
  for (int i = 0; i < 8; ++i) {
    int nl = i * 4 + (t >> 6);
    int n = ng * 32 + nl;
    int p = pt * 64 + (t & 63);
    float acc = 0.f;
#pragma unroll
    for (int z = 0; z < KSPLIT; ++z)
      acc += P[(size_t)z * (DS * DI) + (size_t)n * DI + p];
    tile[nl][t & 63] = acc;
  }
  __syncthreads();
#pragma unroll
  for (int j = 0; j < 8; ++j) {
    int linear = j * 256 + t;
    int pl = linear >> 5, nl = linear & 31;
    Ht[(size_t)(pt * 64 + pl) * DS + ng * 32 + nl] = f2bf(tile[nl][pl]);
  }
}

// ---------------------------------------------------------------------------
// LayerNorm over 2048 (bf16 y) + z-gate; bf16 yz into zx cols [2048,3072)
// ---------------------------------------------------------------------------
__global__ __launch_bounds__(256)
void ln_mul_kernel(const unsigned short* __restrict__ ybuf, float* __restrict__ zx,
                   const float* __restrict__ ln_w, const float* __restrict__ ln_b) {
  int l = blockIdx.x;
  int t = threadIdx.x;
  const unsigned short* yrow = ybuf + (size_t)l * DI;
  float vals[8];
  float s = 0.f, sq = 0.f;
#pragma unroll
  for (int i = 0; i < 8; ++i) {
    float v = bf2f(yrow[t + i * 256]);
    vals[i] = v;
    s += v;
    sq += v * v;
  }
#pragma unroll
  for (int off = 32; off > 0; off >>= 1) {
    s += __shfl_down(s, off, 64);
    sq += __shfl_down(sq, off, 64);
  }
  __shared__ float red[10];
  int wave = t >> 6, lane = t & 63;
  if (lane == 0) { red[wave] = s; red[4 + wave] = sq; }
  __syncthreads();
  if (t == 0) {
    float S = red[0] + red[1] + red[2] + red[3];
    float SQ = red[4] + red[5] + red[6] + red[7];
    float mu = S / (float)DI;
    red[8] = mu;
    red[9] = rsqrtf(SQ / (float)DI - mu * mu + 1e-5f);
  }
  __syncthreads();
  float mu = red[8], rstd = red[9];
  float* zrow = zx + (size_t)l * DPROJ;
  unsigned short* yzb = (unsigned short*)(zrow + DI);
#pragma unroll
  for (int i = 0; i < 8; ++i) {
    int c = t + i * 256;
    float v = (vals[i] - mu) * rstd * ln_w[c] + ln_b[c];
    yzb[c] = f2bf(v * zrow[c]);
  }
}

// ---------------------------------------------------------------------------
extern "C" void kernel_launch(void* const* d_in, const int* in_sizes, int n_in,
                              void* d_out, int out_size, void* d_ws, size_t ws_size,
                              hipStream_t stream) {
  const float* x       = (const float*)d_in[0];
  const float* W_in    = (const float*)d_in[1];
  const float* W_conv  = (const float*)d_in[2];
  const float* b_conv  = (const float*)d_in[3];
  const float* dt_bias = (const float*)d_in[4];
  const float* A_log   = (const float*)d_in[5];
  const float* D_param = (const float*)d_in[6];
  const float* ln_w    = (const float*)d_in[7];
  const float* ln_b    = (const float*)d_in[8];
  const float* W_out   = (const float*)d_in[9];
  float* out = (float*)d_out;

  // ---- workspace layout (~239.6 MB; r1 proved >=243 MB works) ----
  float* ws = (float*)d_ws;
  float* zx = ws;                                        // L*4384 f32
  float* p1 = zx + (size_t)L_SEQ * DPROJ;
  unsigned short* xs = (unsigned short*)p1;              // L*2048 bf16
  float* p2 = p1 + (size_t)L_SEQ * DI / 2;
  unsigned short* bmat = (unsigned short*)p2;            // L*128 bf16
  float* p3 = p2 + (size_t)L_SEQ * DS / 2;
  unsigned short* cb = (unsigned short*)p3;              // L*128 bf16
  float* p4 = p3 + (size_t)L_SEQ * DS / 2;
  float* svec = p4;                                      // L*32 f32
  float* p5 = p4 + (size_t)L_SEQ * NH;
  unsigned short* OpT = (unsigned short*)p5;             // 2176*8192 bf16
  float* p6 = p5 + (size_t)OPROWS * L_SEQ / 2;
  float* Ppart = p6;                                     // 16*128*2048 f32
  float* p7 = p6 + (size_t)KSPLIT * DS * DI;
  unsigned short* Ht = (unsigned short*)p7;              // 2048*128 bf16
  float* p8 = p7 + (size_t)DI * DS / 2;
  unsigned short* wout_bf16 = (unsigned short*)p8;       // 1024*2048 bf16
  // aliases in OpT's dead windows:
  unsigned short* x_bf16   = OpT;                        // casts..GEMM1
  unsigned short* win_bf16 = OpT + (size_t)L_SEQ * DM;   // casts..GEMM1
  unsigned short* ybuf     = OpT;                        // Y-GEMM..ln_mul

  // 0) casts
  cast_bf16_kernel<<<(L_SEQ * DM) / 1024, 256, 0, stream>>>(x, x_bf16);
  cast_win_pad_kernel<<<(NPAD_IN * DM) / 1024, 256, 0, stream>>>(W_in, win_bf16);
  cast_bf16_kernel<<<(DM * DI) / 1024, 256, 0, stream>>>(W_out, wout_bf16);

  // 1) zx = x @ W_in^T  (M=8192, N=4480 pad, K=1024)
  gemm_bt_mfma<0><<<dim3(NPAD_IN / 128, L_SEQ / 128), 256, 0, stream>>>(
      x_bf16, DM, win_bf16, DM, zx, DPROJ, DM, DPROJ, nullptr, nullptr);

  // 2) s = a*dt
  dt_kernel<<<(L_SEQ * NH) / 256, 256, 0, stream>>>(zx, dt_bias, A_log, svec);

  // 3) conv + silu
  conv_silu_kernel<<<dim3(CDIM / 256, L_SEQ), 256, 0, stream>>>(
      zx, W_conv, b_conv, xs, bmat, cb);

  // 4) [Vs^T; B^T]  (clobbers x_bf16/win_bf16 — dead)
  transpose_pack_kernel<<<dim3(OPROWS / 64, L_SEQ / 64), 256, 0, stream>>>(
      xs, bmat, svec, OpT);

  // 5) Hcat = B^T @ Vs : M=128, N=2048, K=8192, split-K=16
  gemm_bt_mfma<2><<<dim3(DI / 128, 1, KSPLIT), 256, 0, stream>>>(
      OpT + (size_t)DI * L_SEQ, L_SEQ, OpT, L_SEQ, Ppart, DI, L_SEQ, DI,
      nullptr, nullptr);

  // 6) reduce partials + transpose -> Ht (2048 x 128 bf16)
  h_reduce_t_kernel<<<128, 256, 0, stream>>>(Ppart, Ht);

  // 7) y = C @ Hcat + D*x_ssm : M=8192, N=2048, K=128, bf16 out (ybuf = OpT alias)
  gemm_bt_mfma<1><<<dim3(DI / 128, L_SEQ / 128), 256, 0, stream>>>(
      cb, DS, Ht, DS, ybuf, DI, DS, DI, xs, D_param);

  // 8) LN + z-gate -> bf16 yz into zx cols [2048,3072)
  ln_mul_kernel<<<L_SEQ, 256, 0, stream>>>(ybuf, zx, ln_w, ln_b);

  // 9) out = yz @ W_out^T : M=8192, N=1024, K=2048
  gemm_bt_mfma<0><<<dim3(DM / 128, L_SEQ / 128), 256, 0, stream>>>(
      (unsigned short*)(zx + DI), DPROJ * 2, wout_bf16, DI, out, DM, DI, DM,
      nullptr, nullptr);
}

// Round 4
// 453.858 us; speedup vs baseline: 5.3991x; 1.0353x over previous
//
#include <hip/hip_runtime.h>
#include <hip/hip_bf16.h>
#include <math.h>

#define L_SEQ 8192
#define DM 1024
#define DI 2048
#define NH 32
#define HD 64
#define DS 128
#define CDIM 2304
#define DPROJ 4384
#define NPAD_IN 4480  // 35*128, zero-padded W_in rows
#define KSPLIT 16
#define OPROWS 2176   // 2048 Vs^T rows + 128 B^T rows

typedef short bf16x8 __attribute__((ext_vector_type(8)));
typedef float floatx4 __attribute__((ext_vector_type(4)));
typedef unsigned short u16x4 __attribute__((ext_vector_type(4)));
typedef unsigned short u16x8 __attribute__((ext_vector_type(8)));

#define AS1(p) ((const __attribute__((address_space(1))) void*)(p))
#define AS3(p) ((__attribute__((address_space(3))) void*)(p))

__device__ __forceinline__ float bf2f(unsigned short u) {
  union { unsigned int i; float f; } c; c.i = ((unsigned int)u) << 16; return c.f;
}
__device__ __forceinline__ unsigned short f2bf(float f) {
  return __bfloat16_as_ushort(__float2bfloat16(f));
}

// ---------------------------------------------------------------------------
// bf16 MFMA GEMM: C[m,n] = sum_k A[m,k]*B[n,k]  (K contiguous both operands)
// 128x128 tile, BK=32, 4 waves (2x2), 4x4 frags of 16x16x32 each.
// MODE 0: bf16 out, LDS-repacked coalesced ushort8 stores, 8-col-run guard
//         (gcol < Nstore; Nstore % 8 == 0 so runs are all-or-nothing).
// MODE 1: bf16 out, repacked, fused addend  + Dvec[gcol>>6]*bf16(xs[m*ldc+gcol]).
// MODE 2: f32 out, split-K: blockIdx.z picks K-chunk & partial slice (scattered).
// MODE 3: f32 out, scattered stores with col guard.
// ---------------------------------------------------------------------------
template <int MODE>
__global__ __launch_bounds__(256)
void gemm_bt_mfma(const unsigned short* __restrict__ A, int lda,
                  const unsigned short* __restrict__ B, int ldb,
                  void* __restrict__ Cout, int ldc,
                  int Kfull, int Nstore,
                  const unsigned short* __restrict__ xs,
                  const float* __restrict__ Dvec) {
  __shared__ unsigned short smem[2 * 128 * 32];  // 16 KB: K-loop staging + repack
  unsigned short* Asm = smem;
  unsigned short* Bsm = smem + 128 * 32;
  const int t = threadIdx.x;
  const int m0 = blockIdx.y * 128;
  const int n0 = blockIdx.x * 128;
  int kstart = 0, klen = Kfull;
  if (MODE == 2) { klen = Kfull / KSPLIT; kstart = blockIdx.z * klen; }
  const int wave = t >> 6, lane = t & 63;
  const int wm = (wave & 1) * 64;
  const int wn = (wave >> 1) * 64;
  const int fr = lane & 15;
  const int quad = lane >> 4;

  floatx4 acc[4][4];
#pragma unroll
  for (int i = 0; i < 4; ++i)
#pragma unroll
    for (int j = 0; j < 4; ++j) acc[i][j] = (floatx4){0.f, 0.f, 0.f, 0.f};

  for (int k0 = kstart; k0 < kstart + klen; k0 += 32) {
#pragma unroll
    for (int i = 0; i < 2; ++i) {
      int linear = i * 256 + t;          // 0..511
      int row = linear >> 2;             // 0..127
      int kq = (linear & 3) * 8;         // bf16 elem offset in K
      const unsigned short* ga = A + (size_t)(m0 + row) * lda + (k0 + kq);
      const unsigned short* gb = B + (size_t)(n0 + row) * ldb + (k0 + kq);
      __builtin_amdgcn_global_load_lds(AS1(ga), AS3(&Asm[linear * 8]), 16, 0, 0);
      __builtin_amdgcn_global_load_lds(AS1(gb), AS3(&Bsm[linear * 8]), 16, 0, 0);
    }
    __syncthreads();

    bf16x8 af[4], bfr[4];
#pragma unroll
    for (int i = 0; i < 4; ++i) {
      af[i]  = *(const bf16x8*)&Asm[(wm + i * 16 + fr) * 32 + quad * 8];
      bfr[i] = *(const bf16x8*)&Bsm[(wn + i * 16 + fr) * 32 + quad * 8];
    }
#pragma unroll
    for (int mi = 0; mi < 4; ++mi)
#pragma unroll
      for (int ni = 0; ni < 4; ++ni)
        acc[mi][ni] = __builtin_amdgcn_mfma_f32_16x16x32_bf16(
            af[mi], bfr[ni], acc[mi][ni], 0, 0, 0);
    __syncthreads();
  }

  // C/D frag layout: col = lane&15, row = (lane>>4)*4 + r  [m89-verified]
  if (MODE == 0 || MODE == 1) {
    // Repack through LDS (32 rows x 128 cols bf16 per mi-group), then
    // linear-sweep ushort8 stores -> full 128-B-line coalesced writes.
    unsigned short(*rp)[136] = (unsigned short(*)[136])smem;  // 8704 B used
    unsigned short* C = (unsigned short*)Cout;
    const int lrbase = (wm ? 16 : 0) + quad * 4;
#pragma unroll
    for (int mi = 0; mi < 4; ++mi) {
      __syncthreads();  // prior sweep / K-loop reads done
#pragma unroll
      for (int ni = 0; ni < 4; ++ni)
#pragma unroll
        for (int r = 0; r < 4; ++r)
          rp[lrbase + r][wn + ni * 16 + fr] = f2bf(acc[mi][ni][r]);
      __syncthreads();
#pragma unroll
      for (int j = 0; j < 2; ++j) {
        int off = j * 2048 + t * 8;          // elem in 32x128 group
        int lr = off >> 7, c = off & 127;
        int grow = m0 + (lr >> 4) * 64 + mi * 16 + (lr & 15);
        int gcol = n0 + c;
        u16x8 v = *(const u16x8*)&rp[lr][c];
        if (MODE == 1) {
          u16x8 xv = *(const u16x8*)&xs[(size_t)grow * ldc + gcol];
          float Dh = Dvec[gcol >> 6];
          u16x8 o;
#pragma unroll
          for (int e = 0; e < 8; ++e) o[e] = f2bf(bf2f(v[e]) + Dh * bf2f(xv[e]));
          *(u16x8*)&C[(size_t)grow * ldc + gcol] = o;
        } else {
          if (gcol < Nstore) *(u16x8*)&C[(size_t)grow * ldc + gcol] = v;
        }
      }
    }
  } else {
    float* C = (float*)Cout;
    if (MODE == 2) C += (size_t)blockIdx.z * DS * DI;
#pragma unroll
    for (int mi = 0; mi < 4; ++mi)
#pragma unroll
      for (int ni = 0; ni < 4; ++ni) {
        int col = n0 + wn + ni * 16 + fr;
        if (MODE == 2 || col < Nstore) {
          size_t base = (size_t)(m0 + wm + mi * 16 + quad * 4) * ldc + col;
#pragma unroll
          for (int r = 0; r < 4; ++r) C[base + (size_t)r * ldc] = acc[mi][ni][r];
        }
      }
  }
}

// ---------------------------------------------------------------------------
__global__ __launch_bounds__(256)
void cast_bf16_kernel(const float* __restrict__ in, unsigned short* __restrict__ out) {
  size_t i4 = ((size_t)blockIdx.x * 256 + threadIdx.x) * 4;
  float4 v = *(const float4*)(in + i4);
  u16x4 o;
  o.x = f2bf(v.x); o.y = f2bf(v.y); o.z = f2bf(v.z); o.w = f2bf(v.w);
  *(u16x4*)(out + i4) = o;
}

__global__ __launch_bounds__(256)
void cast_win_pad_kernel(const float* __restrict__ in, unsigned short* __restrict__ out) {
  size_t i4 = ((size_t)blockIdx.x * 256 + threadIdx.x) * 4;  // over 4480*1024
  int row = (int)(i4 >> 10);
  u16x4 o = (u16x4){0, 0, 0, 0};
  if (row < DPROJ) {
    float4 v = *(const float4*)(in + i4);
    o.x = f2bf(v.x); o.y = f2bf(v.y); o.z = f2bf(v.z); o.w = f2bf(v.w);
  }
  *(u16x4*)(out + i4) = o;
}

// ---------------------------------------------------------------------------
// s[l,h] = dt * exp(-dt*exp(A_log[h])),  dt = softplus(zxb[l,4352+h]+dt_bias[h])
// ---------------------------------------------------------------------------
__global__ __launch_bounds__(256)
void dt_kernel(const unsigned short* __restrict__ zxb, const float* __restrict__ dt_bias,
               const float* __restrict__ A_log, float* __restrict__ s_out) {
  int idx = blockIdx.x * 256 + threadIdx.x;  // l*32 + h
  int l = idx >> 5, h = idx & 31;
  float v = bf2f(zxb[(size_t)l * DPROJ + (DI + CDIM) + h]) + dt_bias[h];
  float d = (v > 20.f) ? v : log1pf(expf(v));
  s_out[idx] = d * expf(-d * expf(A_log[h]));
}

// ---------------------------------------------------------------------------
// conv+silu (bf16 in) -> bf16: xs (L x 2048), bmat (L x 128), cb (L x 128)
// ---------------------------------------------------------------------------
__global__ __launch_bounds__(256)
void conv_silu_kernel(const unsigned short* __restrict__ zxb, const float* __restrict__ Wc,
                      const float* __restrict__ bc,
                      unsigned short* __restrict__ xs,
                      unsigned short* __restrict__ bmat,
                      unsigned short* __restrict__ cb) {
  int c = blockIdx.x * 256 + threadIdx.x;  // 0..2303
  int l = blockIdx.y;
  float s = bc[c];
#pragma unroll
  for (int j = 0; j < 4; ++j) {
    int ll = l - 1 + j;
    if (ll >= 0 && ll < L_SEQ)
      s += bf2f(zxb[(size_t)ll * DPROJ + DI + c]) * Wc[c * 4 + j];
  }
  float v = s / (1.f + expf(-s));
  unsigned short b = f2bf(v);
  if (c < DI)            xs[(size_t)l * DI + c] = b;
  else if (c < DI + DS)  bmat[(size_t)l * DS + (c - DI)] = b;
  else                   cb[(size_t)l * DS + (c - DI - DS)] = b;
}

// ---------------------------------------------------------------------------
// OpT[r][l]: r<2048 -> s[l,r>>6]*xs[l,r]; r in [2048,2176) -> bmat[l,r-2048]
// ---------------------------------------------------------------------------
__global__ __launch_bounds__(256)
void transpose_pack_kernel(const unsigned short* __restrict__ xs,
                           const unsigned short* __restrict__ bmat,
                           const float* __restrict__ s,
                           unsigned short* __restrict__ OpT) {
  __shared__ float tile[64][65];
  const int r0 = blockIdx.x * 64;
  const int l0 = blockIdx.y * 64;
  const int t = threadIdx.x;
  const bool isB = (r0 >= DI);
#pragma unroll
  for (int i = 0; i < 16; ++i) {
    int idx = i * 256 + t;
    int ro = idx & 63;
    int lo = idx >> 6;
    int l = l0 + lo;
    float v;
    if (isB) v = bf2f(bmat[(size_t)l * DS + (r0 - DI + ro)]);
    else     v = bf2f(xs[(size_t)l * DI + r0 + ro]) * s[(size_t)l * NH + (r0 >> 6)];
    tile[ro][lo] = v;
  }
  __syncthreads();
#pragma unroll
  for (int j = 0; j < 4; ++j) {
    int linear = j * 1024 + t * 4;
    int rr = linear >> 6;
    int lc = linear & 63;
    u16x4 o;
    o.x = f2bf(tile[rr][lc + 0]);
    o.y = f2bf(tile[rr][lc + 1]);
    o.z = f2bf(tile[rr][lc + 2]);
    o.w = f2bf(tile[rr][lc + 3]);
    *(u16x4*)&OpT[(size_t)(r0 + rr) * L_SEQ + l0 + lc] = o;
  }
}

// ---------------------------------------------------------------------------
// Ht[p][n] = bf16( sum_z Ppart[z][n][p] )
// ---------------------------------------------------------------------------
__global__ __launch_bounds__(256)
void h_reduce_t_kernel(const float* __restrict__ P, unsigned short* __restrict__ Ht) {
  __shared__ float tile[32][65];
  const int bid = blockIdx.x;
  const int pt = bid & 31, ng = bid >> 5;
  const int t = threadIdx.x;
#pragma unroll
  for (int i = 0; i < 8; ++i) {
    int nl = i * 4 + (t >> 6);
    int n = ng * 32 + nl;
    int p = pt * 64 + (t & 63);
    float acc = 0.f;
#pragma unroll
    for (int z = 0; z < KSPLIT; ++z)
      acc += P[(size_t)z * (DS * DI) + (size_t)n * DI + p];
    tile[nl][t & 63] = acc;
  }
  __syncthreads();
#pragma unroll
  for (int j = 0; j < 8; ++j) {
    int linear = j * 256 + t;
    int pl = linear >> 5, nl = linear & 31;
    Ht[(size_t)(pt * 64 + pl) * DS + ng * 32 + nl] = f2bf(tile[nl][pl]);
  }
}

// ---------------------------------------------------------------------------
// LayerNorm over 2048 (bf16 y) + z-gate (bf16 z); bf16 yz into zxb cols [2048,4096)
// ---------------------------------------------------------------------------
__global__ __launch_bounds__(256)
void ln_mul_kernel(const unsigned short* __restrict__ ybuf, unsigned short* __restrict__ zxb,
                   const float* __restrict__ ln_w, const float* __restrict__ ln_b) {
  int l = blockIdx.x;
  int t = threadIdx.x;
  const unsigned short* yrow = ybuf + (size_t)l * DI;
  float vals[8];
  float s = 0.f, sq = 0.f;
#pragma unroll
  for (int i = 0; i < 8; ++i) {
    float v = bf2f(yrow[t + i * 256]);
    vals[i] = v;
    s += v;
    sq += v * v;
  }
#pragma unroll
  for (int off = 32; off > 0; off >>= 1) {
    s += __shfl_down(s, off, 64);
    sq += __shfl_down(sq, off, 64);
  }
  __shared__ float red[10];
  int wave = t >> 6, lane = t & 63;
  if (lane == 0) { red[wave] = s; red[4 + wave] = sq; }
  __syncthreads();
  if (t == 0) {
    float S = red[0] + red[1] + red[2] + red[3];
    float SQ = red[4] + red[5] + red[6] + red[7];
    float mu = S / (float)DI;
    red[8] = mu;
    red[9] = rsqrtf(SQ / (float)DI - mu * mu + 1e-5f);
  }
  __syncthreads();
  float mu = red[8], rstd = red[9];
  unsigned short* zrow = zxb + (size_t)l * DPROJ;
  unsigned short* yzb = zrow + DI;
#pragma unroll
  for (int i = 0; i < 8; ++i) {
    int c = t + i * 256;
    float v = (vals[i] - mu) * rstd * ln_w[c] + ln_b[c];
    yzb[c] = f2bf(v * bf2f(zrow[c]));
  }
}

// ---------------------------------------------------------------------------
extern "C" void kernel_launch(void* const* d_in, const int* in_sizes, int n_in,
                              void* d_out, int out_size, void* d_ws, size_t ws_size,
                              hipStream_t stream) {
  const float* x       = (const float*)d_in[0];
  const float* W_in    = (const float*)d_in[1];
  const float* W_conv  = (const float*)d_in[2];
  const float* b_conv  = (const float*)d_in[3];
  const float* dt_bias = (const float*)d_in[4];
  const float* A_log   = (const float*)d_in[5];
  const float* D_param = (const float*)d_in[6];
  const float* ln_w    = (const float*)d_in[7];
  const float* ln_b    = (const float*)d_in[8];
  const float* W_out   = (const float*)d_in[9];
  float* out = (float*)d_out;

  // ---- workspace layout (~168 MB) ----
  unsigned short* zxb = (unsigned short*)d_ws;           // L*4384 bf16
  unsigned short* xs   = zxb + (size_t)L_SEQ * DPROJ;    // L*2048 bf16
  unsigned short* bmat = xs + (size_t)L_SEQ * DI;        // L*128 bf16
  unsigned short* cb   = bmat + (size_t)L_SEQ * DS;      // L*128 bf16
  float* svec = (float*)(cb + (size_t)L_SEQ * DS);       // L*32 f32
  unsigned short* OpT = (unsigned short*)(svec + (size_t)L_SEQ * NH);  // 2176*8192 bf16
  float* Ppart = (float*)(OpT + (size_t)OPROWS * L_SEQ); // 16*128*2048 f32
  unsigned short* Ht = (unsigned short*)(Ppart + (size_t)KSPLIT * DS * DI);  // 2048*128
  unsigned short* wout_bf16 = Ht + (size_t)DI * DS;      // 1024*2048 bf16
  // aliases in OpT's dead windows:
  unsigned short* x_bf16   = OpT;                        // casts..GEMM1 (16 MB)
  unsigned short* win_bf16 = OpT + (size_t)L_SEQ * DM;   // casts..GEMM1 (9.2 MB)
  unsigned short* ybuf     = OpT;                        // Y-GEMM..ln_mul (33.5 MB)

  // 0) casts
  cast_bf16_kernel<<<(L_SEQ * DM) / 1024, 256, 0, stream>>>(x, x_bf16);
  cast_win_pad_kernel<<<(NPAD_IN * DM) / 1024, 256, 0, stream>>>(W_in, win_bf16);
  cast_bf16_kernel<<<(DM * DI) / 1024, 256, 0, stream>>>(W_out, wout_bf16);

  // 1) zxb = bf16( x @ W_in^T )  (M=8192, N=4480 pad, K=1024) — repacked stores
  gemm_bt_mfma<0><<<dim3(NPAD_IN / 128, L_SEQ / 128), 256, 0, stream>>>(
      x_bf16, DM, win_bf16, DM, zxb, DPROJ, DM, DPROJ, nullptr, nullptr);

  // 2) s = a*dt
  dt_kernel<<<(L_SEQ * NH) / 256, 256, 0, stream>>>(zxb, dt_bias, A_log, svec);

  // 3) conv + silu
  conv_silu_kernel<<<dim3(CDIM / 256, L_SEQ), 256, 0, stream>>>(
      zxb, W_conv, b_conv, xs, bmat, cb);

  // 4) [Vs^T; B^T]  (clobbers x_bf16/win_bf16 — dead)
  transpose_pack_kernel<<<dim3(OPROWS / 64, L_SEQ / 64), 256, 0, stream>>>(
      xs, bmat, svec, OpT);

  // 5) Hcat = B^T @ Vs : M=128, N=2048, K=8192, split-K=16
  gemm_bt_mfma<2><<<dim3(DI / 128, 1, KSPLIT), 256, 0, stream>>>(
      OpT + (size_t)DI * L_SEQ, L_SEQ, OpT, L_SEQ, Ppart, DI, L_SEQ, DI,
      nullptr, nullptr);

  // 6) reduce partials + transpose -> Ht (2048 x 128 bf16)
  h_reduce_t_kernel<<<128, 256, 0, stream>>>(Ppart, Ht);

  // 7) y = C @ Hcat + D*x_ssm : M=8192, N=2048, K=128, bf16 repacked out
  gemm_bt_mfma<1><<<dim3(DI / 128, L_SEQ / 128), 256, 0, stream>>>(
      cb, DS, Ht, DS, ybuf, DI, DS, DI, xs, D_param);

  // 8) LN + z-gate -> bf16 yz into zxb cols [2048,4096)
  ln_mul_kernel<<<L_SEQ, 256, 0, stream>>>(ybuf, zxb, ln_w, ln_b);

  // 9) out = yz @ W_out^T : M=8192, N=1024, K=2048 (f32 out)
  gemm_bt_mfma<3><<<dim3(DM / 128, L_SEQ / 128), 256, 0, stream>>>(
      zxb + DI, DPROJ, wout_bf16, DI, out, DM, DI, DM, nullptr, nullptr);
}

// Round 5
// 390.692 us; speedup vs baseline: 6.2720x; 1.1617x over previous
//
#include <hip/hip_runtime.h>
#include <hip/hip_bf16.h>
#include <math.h>

#define L_SEQ 8192
#define DM 1024
#define DI 2048
#define NH 32
#define HD 64
#define DS 128
#define CDIM 2304
#define DPROJ 4384
#define NPAD_IN 4480  // 35*128, zero-padded W_in rows
#define KSPLIT 16
#define OPROWS 2176   // 2048 Vs^T rows + 128 B^T rows

typedef short bf16x8 __attribute__((ext_vector_type(8)));
typedef float floatx4 __attribute__((ext_vector_type(4)));
typedef unsigned short u16x4 __attribute__((ext_vector_type(4)));
typedef unsigned short u16x8 __attribute__((ext_vector_type(8)));

#define AS1(p) ((const __attribute__((address_space(1))) void*)(p))
#define AS3(p) ((__attribute__((address_space(3))) void*)(p))

__device__ __forceinline__ float bf2f(unsigned short u) {
  union { unsigned int i; float f; } c; c.i = ((unsigned int)u) << 16; return c.f;
}
__device__ __forceinline__ unsigned short f2bf(float f) {
  return __bfloat16_as_ushort(__float2bfloat16(f));
}

// ---------------------------------------------------------------------------
// bf16 MFMA GEMM: C[m,n] = sum_k A[m,k]*B[n,k]  (K contiguous both operands)
// 128x128 tile, BK=32, 4 waves (2x2), 4x4 frags of 16x16x32 each.
// All modes use LDS-repacked coalesced epilogues (no partial-line RFO):
// MODE 0: bf16 out, ushort8 sweep, 8-col-run guard (Nstore % 8 == 0).
// MODE 1: bf16 out, ushort8 sweep, fused + Dvec[gcol>>6]*bf16(xs[...]).
// MODE 2: f32 out, float4 sweep, split-K (blockIdx.z -> K-chunk & slice).
// MODE 3: f32 out, float4 sweep (grid must cover N exactly).
// ---------------------------------------------------------------------------
template <int MODE>
__global__ __launch_bounds__(256)
void gemm_bt_mfma(const unsigned short* __restrict__ A, int lda,
                  const unsigned short* __restrict__ B, int ldb,
                  void* __restrict__ Cout, int ldc,
                  int Kfull, int Nstore,
                  const unsigned short* __restrict__ xs,
                  const float* __restrict__ Dvec) {
  __shared__ __align__(16) char smem[17408];  // staging 16 KB; f32 repack 17 KB
  unsigned short* Asm = (unsigned short*)smem;
  unsigned short* Bsm = Asm + 128 * 32;
  const int t = threadIdx.x;
  const int m0 = blockIdx.y * 128;
  const int n0 = blockIdx.x * 128;
  int kstart = 0, klen = Kfull;
  if (MODE == 2) { klen = Kfull / KSPLIT; kstart = blockIdx.z * klen; }
  const int wave = t >> 6, lane = t & 63;
  const int wm = (wave & 1) * 64;
  const int wn = (wave >> 1) * 64;
  const int fr = lane & 15;
  const int quad = lane >> 4;

  floatx4 acc[4][4];
#pragma unroll
  for (int i = 0; i < 4; ++i)
#pragma unroll
    for (int j = 0; j < 4; ++j) acc[i][j] = (floatx4){0.f, 0.f, 0.f, 0.f};

  for (int k0 = kstart; k0 < kstart + klen; k0 += 32) {
#pragma unroll
    for (int i = 0; i < 2; ++i) {
      int linear = i * 256 + t;          // 0..511
      int row = linear >> 2;             // 0..127
      int kq = (linear & 3) * 8;         // bf16 elem offset in K
      const unsigned short* ga = A + (size_t)(m0 + row) * lda + (k0 + kq);
      const unsigned short* gb = B + (size_t)(n0 + row) * ldb + (k0 + kq);
      __builtin_amdgcn_global_load_lds(AS1(ga), AS3(&Asm[linear * 8]), 16, 0, 0);
      __builtin_amdgcn_global_load_lds(AS1(gb), AS3(&Bsm[linear * 8]), 16, 0, 0);
    }
    __syncthreads();

    bf16x8 af[4], bfr[4];
#pragma unroll
    for (int i = 0; i < 4; ++i) {
      af[i]  = *(const bf16x8*)&Asm[(wm + i * 16 + fr) * 32 + quad * 8];
      bfr[i] = *(const bf16x8*)&Bsm[(wn + i * 16 + fr) * 32 + quad * 8];
    }
#pragma unroll
    for (int mi = 0; mi < 4; ++mi)
#pragma unroll
      for (int ni = 0; ni < 4; ++ni)
        acc[mi][ni] = __builtin_amdgcn_mfma_f32_16x16x32_bf16(
            af[mi], bfr[ni], acc[mi][ni], 0, 0, 0);
    __syncthreads();
  }

  // C/D frag layout: col = lane&15, row = (lane>>4)*4 + r  [m89-verified]
  const int lrbase = (wm ? 16 : 0) + quad * 4;
  if (MODE == 0 || MODE == 1) {
    unsigned short(*rp)[136] = (unsigned short(*)[136])smem;
    unsigned short* C = (unsigned short*)Cout;
#pragma unroll
    for (int mi = 0; mi < 4; ++mi) {
      __syncthreads();
#pragma unroll
      for (int ni = 0; ni < 4; ++ni)
#pragma unroll
        for (int r = 0; r < 4; ++r)
          rp[lrbase + r][wn + ni * 16 + fr] = f2bf(acc[mi][ni][r]);
      __syncthreads();
#pragma unroll
      for (int j = 0; j < 2; ++j) {
        int off = j * 2048 + t * 8;          // elem in 32x128 group
        int lr = off >> 7, c = off & 127;
        int grow = m0 + (lr >> 4) * 64 + mi * 16 + (lr & 15);
        int gcol = n0 + c;
        u16x8 v = *(const u16x8*)&rp[lr][c];
        if (MODE == 1) {
          u16x8 xv = *(const u16x8*)&xs[(size_t)grow * ldc + gcol];
          float Dh = Dvec[gcol >> 6];
          u16x8 o;
#pragma unroll
          for (int e = 0; e < 8; ++e) o[e] = f2bf(bf2f(v[e]) + Dh * bf2f(xv[e]));
          *(u16x8*)&C[(size_t)grow * ldc + gcol] = o;
        } else {
          if (gcol < Nstore) *(u16x8*)&C[(size_t)grow * ldc + gcol] = v;
        }
      }
    }
  } else {
    float(*rpf)[136] = (float(*)[136])smem;  // 32*136*4 = 17408 B
    float* C = (float*)Cout;
    if (MODE == 2) C += (size_t)blockIdx.z * DS * DI;
#pragma unroll
    for (int mi = 0; mi < 4; ++mi) {
      __syncthreads();
#pragma unroll
      for (int ni = 0; ni < 4; ++ni)
#pragma unroll
        for (int r = 0; r < 4; ++r)
          rpf[lrbase + r][wn + ni * 16 + fr] = acc[mi][ni][r];
      __syncthreads();
#pragma unroll
      for (int j = 0; j < 4; ++j) {
        int off = j * 1024 + t * 4;          // elem in 32x128 group
        int lr = off >> 7, c = off & 127;
        int grow = m0 + (lr >> 4) * 64 + mi * 16 + (lr & 15);
        int gcol = n0 + c;
        float4 v = *(const float4*)&rpf[lr][c];
        *(float4*)&C[(size_t)grow * ldc + gcol] = v;
      }
    }
  }
}

// ---------------------------------------------------------------------------
__global__ __launch_bounds__(256)
void cast_bf16_kernel(const float* __restrict__ in, unsigned short* __restrict__ out) {
  size_t i4 = ((size_t)blockIdx.x * 256 + threadIdx.x) * 4;
  float4 v = *(const float4*)(in + i4);
  u16x4 o;
  o.x = f2bf(v.x); o.y = f2bf(v.y); o.z = f2bf(v.z); o.w = f2bf(v.w);
  *(u16x4*)(out + i4) = o;
}

__global__ __launch_bounds__(256)
void cast_win_pad_kernel(const float* __restrict__ in, unsigned short* __restrict__ out) {
  size_t i4 = ((size_t)blockIdx.x * 256 + threadIdx.x) * 4;  // over 4480*1024
  int row = (int)(i4 >> 10);
  u16x4 o = (u16x4){0, 0, 0, 0};
  if (row < DPROJ) {
    float4 v = *(const float4*)(in + i4);
    o.x = f2bf(v.x); o.y = f2bf(v.y); o.z = f2bf(v.z); o.w = f2bf(v.w);
  }
  *(u16x4*)(out + i4) = o;
}

// ---------------------------------------------------------------------------
// s[l,h] = dt * exp(-dt*exp(A_log[h])),  dt = softplus(zxb[l,4352+h]+dt_bias[h])
// ---------------------------------------------------------------------------
__global__ __launch_bounds__(256)
void dt_kernel(const unsigned short* __restrict__ zxb, const float* __restrict__ dt_bias,
               const float* __restrict__ A_log, float* __restrict__ s_out) {
  int idx = blockIdx.x * 256 + threadIdx.x;  // l*32 + h
  int l = idx >> 5, h = idx & 31;
  float v = bf2f(zxb[(size_t)l * DPROJ + (DI + CDIM) + h]) + dt_bias[h];
  float d = (v > 20.f) ? v : log1pf(expf(v));
  s_out[idx] = d * expf(-d * expf(A_log[h]));
}

// ---------------------------------------------------------------------------
// conv+silu, l-tiled: block = 256 channels x 16 l's, LDS-staged 19 input rows.
// Read amplification 19/16 vs 4x in the naive per-l version.
// ---------------------------------------------------------------------------
__global__ __launch_bounds__(256)
void conv_silu_kernel(const unsigned short* __restrict__ zxb, const float* __restrict__ Wc,
                      const float* __restrict__ bc,
                      unsigned short* __restrict__ xs,
                      unsigned short* __restrict__ bmat,
                      unsigned short* __restrict__ cb) {
  __shared__ unsigned short zt[19][256];  // rows l0-1 .. l0+17
  const int c0 = blockIdx.x * 256;
  const int l0 = blockIdx.y * 16;
  const int t = threadIdx.x;
#pragma unroll
  for (int i = 0; i < 5; ++i) {
    int idx = i * 256 + t;                // vec4 index over 19*64
    if (idx < 19 * 64) {
      int row = idx >> 6;
      int col = (idx & 63) * 4;
      int gl = l0 - 1 + row;
      u16x4 v = (u16x4){0, 0, 0, 0};
      if (gl >= 0 && gl < L_SEQ)
        v = *(const u16x4*)&zxb[(size_t)gl * DPROJ + DI + c0 + col];
      *(u16x4*)&zt[row][col] = v;
    }
  }
  const int c = c0 + t;
  const float4 wv = *(const float4*)&Wc[c * 4];
  const float bias = bc[c];
  __syncthreads();
#pragma unroll
  for (int i = 0; i < 16; ++i) {
    int l = l0 + i;
    float s = bias + bf2f(zt[i + 0][t]) * wv.x + bf2f(zt[i + 1][t]) * wv.y +
              bf2f(zt[i + 2][t]) * wv.z + bf2f(zt[i + 3][t]) * wv.w;
    float v = s / (1.f + expf(-s));
    unsigned short b = f2bf(v);
    if (c < DI)            xs[(size_t)l * DI + c] = b;
    else if (c < DI + DS)  bmat[(size_t)l * DS + (c - DI)] = b;
    else                   cb[(size_t)l * DS + (c - DI - DS)] = b;
  }
}

// ---------------------------------------------------------------------------
// OpT[r][l]: r<2048 -> s[l,r>>6]*xs[l,r]; r in [2048,2176) -> bmat[l,r-2048]
// 64x64 tiles; vectorized u16x4 global loads (head is uniform per block).
// ---------------------------------------------------------------------------
__global__ __launch_bounds__(256)
void transpose_pack_kernel(const unsigned short* __restrict__ xs,
                           const unsigned short* __restrict__ bmat,
                           const float* __restrict__ s,
                           unsigned short* __restrict__ OpT) {
  __shared__ float tile[64][65];
  const int r0 = blockIdx.x * 64;
  const int l0 = blockIdx.y * 64;
  const int t = threadIdx.x;
  const bool isB = (r0 >= DI);
#pragma unroll
  for (int i = 0; i < 4; ++i) {
    int e = i * 1024 + t * 4;
    int lo = e >> 6;
    int ro = e & 63;
    int l = l0 + lo;
    u16x4 v;
    float sl;
    if (isB) {
      v = *(const u16x4*)&bmat[(size_t)l * DS + (r0 - DI) + ro];
      sl = 1.f;
    } else {
      v = *(const u16x4*)&xs[(size_t)l * DI + r0 + ro];
      sl = s[(size_t)l * NH + (r0 >> 6)];
    }
    tile[ro + 0][lo] = bf2f(v.x) * sl;
    tile[ro + 1][lo] = bf2f(v.y) * sl;
    tile[ro + 2][lo] = bf2f(v.z) * sl;
    tile[ro + 3][lo] = bf2f(v.w) * sl;
  }
  __syncthreads();
#pragma unroll
  for (int j = 0; j < 4; ++j) {
    int linear = j * 1024 + t * 4;
    int rr = linear >> 6;
    int lc = linear & 63;
    u16x4 o;
    o.x = f2bf(tile[rr][lc + 0]);
    o.y = f2bf(tile[rr][lc + 1]);
    o.z = f2bf(tile[rr][lc + 2]);
    o.w = f2bf(tile[rr][lc + 3]);
    *(u16x4*)&OpT[(size_t)(r0 + rr) * L_SEQ + l0 + lc] = o;
  }
}

// ---------------------------------------------------------------------------
// Ht[p][n] = bf16( sum_z Ppart[z][n][p] )
// ---------------------------------------------------------------------------
__global__ __launch_bounds__(256)
void h_reduce_t_kernel(const float* __restrict__ P, unsigned short* __restrict__ Ht) {
  __shared__ float tile[32][65];
  const int bid = blockIdx.x;
  const int pt = bid & 31, ng = bid >> 5;
  const int t = threadIdx.x;
#pragma unroll
  for (int i = 0; i < 8; ++i) {
    int nl = i * 4 + (t >> 6);
    int n = ng * 32 + nl;
    int p = pt * 64 + (t & 63);
    float acc = 0.f;
#pragma unroll
    for (int z = 0; z < KSPLIT; ++z)
      acc += P[(size_t)z * (DS * DI) + (size_t)n * DI + p];
    tile[nl][t & 63] = acc;
  }
  __syncthreads();
#pragma unroll
  for (int j = 0; j < 8; ++j) {
    int linear = j * 256 + t;
    int pl = linear >> 5, nl = linear & 31;
    Ht[(size_t)(pt * 64 + pl) * DS + ng * 32 + nl] = f2bf(tile[nl][pl]);
  }
}

// ---------------------------------------------------------------------------
// LayerNorm over 2048 (bf16 y) + z-gate (bf16 z); bf16 yz into zxb [2048,4096);
// fully vectorized u16x8 loads/stores (contiguous 8 elems per thread).
// ---------------------------------------------------------------------------
__global__ __launch_bounds__(256)
void ln_mul_kernel(const unsigned short* __restrict__ ybuf, unsigned short* __restrict__ zxb,
                   const float* __restrict__ ln_w, const float* __restrict__ ln_b) {
  int l = blockIdx.x;
  int t = threadIdx.x;
  int c0 = t * 8;
  u16x8 yv = *(const u16x8*)&ybuf[(size_t)l * DI + c0];
  float vals[8];
  float s = 0.f, sq = 0.f;
#pragma unroll
  for (int i = 0; i < 8; ++i) {
    float v = bf2f(yv[i]);
    vals[i] = v;
    s += v;
    sq += v * v;
  }
#pragma unroll
  for (int off = 32; off > 0; off >>= 1) {
    s += __shfl_down(s, off, 64);
    sq += __shfl_down(sq, off, 64);
  }
  __shared__ float red[10];
  int wave = t >> 6, lane = t & 63;
  if (lane == 0) { red[wave] = s; red[4 + wave] = sq; }
  __syncthreads();
  if (t == 0) {
    float S = red[0] + red[1] + red[2] + red[3];
    float SQ = red[4] + red[5] + red[6] + red[7];
    float mu = S / (float)DI;
    red[8] = mu;
    red[9] = rsqrtf(SQ / (float)DI - mu * mu + 1e-5f);
  }
  __syncthreads();
  float mu = red[8], rstd = red[9];
  unsigned short* zrow = zxb + (size_t)l * DPROJ;
  u16x8 zv = *(const u16x8*)&zrow[c0];
  float4 w0 = *(const float4*)&ln_w[c0], w1 = *(const float4*)&ln_w[c0 + 4];
  float4 b0 = *(const float4*)&ln_b[c0], b1 = *(const float4*)&ln_b[c0 + 4];
  float w[8] = {w0.x, w0.y, w0.z, w0.w, w1.x, w1.y, w1.z, w1.w};
  float b[8] = {b0.x, b0.y, b0.z, b0.w, b1.x, b1.y, b1.z, b1.w};
  u16x8 o;
#pragma unroll
  for (int i = 0; i < 8; ++i) {
    float v = (vals[i] - mu) * rstd * w[i] + b[i];
    o[i] = f2bf(v * bf2f(zv[i]));
  }
  *(u16x8*)&zrow[DI + c0] = o;
}

// ---------------------------------------------------------------------------
extern "C" void kernel_launch(void* const* d_in, const int* in_sizes, int n_in,
                              void* d_out, int out_size, void* d_ws, size_t ws_size,
                              hipStream_t stream) {
  const float* x       = (const float*)d_in[0];
  const float* W_in    = (const float*)d_in[1];
  const float* W_conv  = (const float*)d_in[2];
  const float* b_conv  = (const float*)d_in[3];
  const float* dt_bias = (const float*)d_in[4];
  const float* A_log   = (const float*)d_in[5];
  const float* D_param = (const float*)d_in[6];
  const float* ln_w    = (const float*)d_in[7];
  const float* ln_b    = (const float*)d_in[8];
  const float* W_out   = (const float*)d_in[9];
  float* out = (float*)d_out;

  // ---- workspace layout (~168 MB) ----
  unsigned short* zxb = (unsigned short*)d_ws;           // L*4384 bf16
  unsigned short* xs   = zxb + (size_t)L_SEQ * DPROJ;    // L*2048 bf16
  unsigned short* bmat = xs + (size_t)L_SEQ * DI;        // L*128 bf16
  unsigned short* cb   = bmat + (size_t)L_SEQ * DS;      // L*128 bf16
  float* svec = (float*)(cb + (size_t)L_SEQ * DS);       // L*32 f32
  unsigned short* OpT = (unsigned short*)(svec + (size_t)L_SEQ * NH);  // 2176*8192 bf16
  float* Ppart = (float*)(OpT + (size_t)OPROWS * L_SEQ); // 16*128*2048 f32
  unsigned short* Ht = (unsigned short*)(Ppart + (size_t)KSPLIT * DS * DI);  // 2048*128
  unsigned short* wout_bf16 = Ht + (size_t)DI * DS;      // 1024*2048 bf16
  // aliases in OpT's dead windows:
  unsigned short* x_bf16   = OpT;                        // casts..GEMM1 (16 MB)
  unsigned short* win_bf16 = OpT + (size_t)L_SEQ * DM;   // casts..GEMM1 (9.2 MB)
  unsigned short* ybuf     = OpT;                        // Y-GEMM..ln_mul (33.5 MB)

  // 0) casts
  cast_bf16_kernel<<<(L_SEQ * DM) / 1024, 256, 0, stream>>>(x, x_bf16);
  cast_win_pad_kernel<<<(NPAD_IN * DM) / 1024, 256, 0, stream>>>(W_in, win_bf16);
  cast_bf16_kernel<<<(DM * DI) / 1024, 256, 0, stream>>>(W_out, wout_bf16);

  // 1) zxb = bf16( x @ W_in^T )  (M=8192, N=4480 pad, K=1024)
  gemm_bt_mfma<0><<<dim3(NPAD_IN / 128, L_SEQ / 128), 256, 0, stream>>>(
      x_bf16, DM, win_bf16, DM, zxb, DPROJ, DM, DPROJ, nullptr, nullptr);

  // 2) s = a*dt
  dt_kernel<<<(L_SEQ * NH) / 256, 256, 0, stream>>>(zxb, dt_bias, A_log, svec);

  // 3) conv + silu (l-tiled)
  conv_silu_kernel<<<dim3(CDIM / 256, L_SEQ / 16), 256, 0, stream>>>(
      zxb, W_conv, b_conv, xs, bmat, cb);

  // 4) [Vs^T; B^T]  (clobbers x_bf16/win_bf16 — dead)
  transpose_pack_kernel<<<dim3(OPROWS / 64, L_SEQ / 64), 256, 0, stream>>>(
      xs, bmat, svec, OpT);

  // 5) Hcat = B^T @ Vs : M=128, N=2048, K=8192, split-K=16 (repacked f32 out)
  gemm_bt_mfma<2><<<dim3(DI / 128, 1, KSPLIT), 256, 0, stream>>>(
      OpT + (size_t)DI * L_SEQ, L_SEQ, OpT, L_SEQ, Ppart, DI, L_SEQ, DI,
      nullptr, nullptr);

  // 6) reduce partials + transpose -> Ht (2048 x 128 bf16)
  h_reduce_t_kernel<<<128, 256, 0, stream>>>(Ppart, Ht);

  // 7) y = C @ Hcat + D*x_ssm : M=8192, N=2048, K=128, bf16 repacked out
  gemm_bt_mfma<1><<<dim3(DI / 128, L_SEQ / 128), 256, 0, stream>>>(
      cb, DS, Ht, DS, ybuf, DI, DS, DI, xs, D_param);

  // 8) LN + z-gate -> bf16 yz into zxb cols [2048,4096)
  ln_mul_kernel<<<L_SEQ, 256, 0, stream>>>(ybuf, zxb, ln_w, ln_b);

  // 9) out = yz @ W_out^T : M=8192, N=1024, K=2048 (repacked f32 out)
  gemm_bt_mfma<3><<<dim3(DM / 128, L_SEQ / 128), 256, 0, stream>>>(
      zxb + DI, DPROJ, wout_bf16, DI, out, DM, DI, DM, nullptr, nullptr);
}

// Round 6
// 375.040 us; speedup vs baseline: 6.5337x; 1.0417x over previous
//
#include <hip/hip_runtime.h>
#include <hip/hip_bf16.h>
#include <math.h>

#define L_SEQ 8192
#define DM 1024
#define DI 2048
#define NH 32
#define HD 64
#define DS 128
#define CDIM 2304
#define DPROJ 4384
#define NPAD_IN 4480  // 35*128, zero-padded W_in rows
#define KSPLIT 16
#define OPROWS 2176   // 2048 Vs^T rows + 128 B^T rows

typedef short bf16x8 __attribute__((ext_vector_type(8)));
typedef float floatx4 __attribute__((ext_vector_type(4)));
typedef unsigned short u16x4 __attribute__((ext_vector_type(4)));
typedef unsigned short u16x8 __attribute__((ext_vector_type(8)));

#define AS1(p) ((const __attribute__((address_space(1))) void*)(p))
#define AS3(p) ((__attribute__((address_space(3))) void*)(p))

__device__ __forceinline__ float bf2f(unsigned short u) {
  union { unsigned int i; float f; } c; c.i = ((unsigned int)u) << 16; return c.f;
}
__device__ __forceinline__ unsigned short f2bf(float f) {
  return __bfloat16_as_ushort(__float2bfloat16(f));
}

// ---------------------------------------------------------------------------
// bf16 MFMA GEMM: C[m,n] = sum_k A[m,k]*B[n,k]  (K contiguous both operands)
// 128x128 tile, BK=32, 4 waves (2x2), 4x4 frags of 16x16x32 each.
// XCD-aware swizzle (modes 0/1/3, gy==64): linear id round-robins over 8 XCDs,
// so map xcd=linear&7 to an 8-m-row band, m-fastest within n -> per-XCD L2
// keeps its 8 A-panels resident; each B-panel fetched ~once per XCD.
// All modes use LDS-repacked coalesced epilogues (no partial-line RFO):
// MODE 0: bf16 out, ushort8 sweep, 8-col-run guard (Nstore % 8 == 0).
// MODE 1: bf16 out, ushort8 sweep, fused + Dvec[gcol>>6]*bf16(xs[...]).
// MODE 2: f32 out, float4 sweep, split-K (blockIdx.z -> K-chunk & slice).
// MODE 3: f32 out, float4 sweep (grid must cover N exactly).
// ---------------------------------------------------------------------------
template <int MODE>
__global__ __launch_bounds__(256)
void gemm_bt_mfma(const unsigned short* __restrict__ A, int lda,
                  const unsigned short* __restrict__ B, int ldb,
                  void* __restrict__ Cout, int ldc,
                  int Kfull, int Nstore,
                  const unsigned short* __restrict__ xs,
                  const float* __restrict__ Dvec) {
  __shared__ __align__(16) char smem[17408];  // staging 16 KB; f32 repack 17 KB
  unsigned short* Asm = (unsigned short*)smem;
  unsigned short* Bsm = Asm + 128 * 32;
  const int t = threadIdx.x;

  int bx = blockIdx.x, by = blockIdx.y;
  if (MODE != 2) {
    // gy == 64 for all non-splitK launches here; 64/8 = 8 rows per XCD band.
    int gx = gridDim.x;
    int linear = by * gx + bx;
    int xcd = linear & 7;
    int local = linear >> 3;
    by = xcd * 8 + (local & 7);
    bx = local >> 3;
  }
  const int m0 = by * 128;
  const int n0 = bx * 128;

  int kstart = 0, klen = Kfull;
  if (MODE == 2) { klen = Kfull / KSPLIT; kstart = blockIdx.z * klen; }
  const int wave = t >> 6, lane = t & 63;
  const int wm = (wave & 1) * 64;
  const int wn = (wave >> 1) * 64;
  const int fr = lane & 15;
  const int quad = lane >> 4;

  floatx4 acc[4][4];
#pragma unroll
  for (int i = 0; i < 4; ++i)
#pragma unroll
    for (int j = 0; j < 4; ++j) acc[i][j] = (floatx4){0.f, 0.f, 0.f, 0.f};

  for (int k0 = kstart; k0 < kstart + klen; k0 += 32) {
#pragma unroll
    for (int i = 0; i < 2; ++i) {
      int linear = i * 256 + t;          // 0..511
      int row = linear >> 2;             // 0..127
      int kq = (linear & 3) * 8;         // bf16 elem offset in K
      const unsigned short* ga = A + (size_t)(m0 + row) * lda + (k0 + kq);
      const unsigned short* gb = B + (size_t)(n0 + row) * ldb + (k0 + kq);
      __builtin_amdgcn_global_load_lds(AS1(ga), AS3(&Asm[linear * 8]), 16, 0, 0);
      __builtin_amdgcn_global_load_lds(AS1(gb), AS3(&Bsm[linear * 8]), 16, 0, 0);
    }
    __syncthreads();

    bf16x8 af[4], bfr[4];
#pragma unroll
    for (int i = 0; i < 4; ++i) {
      af[i]  = *(const bf16x8*)&Asm[(wm + i * 16 + fr) * 32 + quad * 8];
      bfr[i] = *(const bf16x8*)&Bsm[(wn + i * 16 + fr) * 32 + quad * 8];
    }
#pragma unroll
    for (int mi = 0; mi < 4; ++mi)
#pragma unroll
      for (int ni = 0; ni < 4; ++ni)
        acc[mi][ni] = __builtin_amdgcn_mfma_f32_16x16x32_bf16(
            af[mi], bfr[ni], acc[mi][ni], 0, 0, 0);
    __syncthreads();
  }

  // C/D frag layout: col = lane&15, row = (lane>>4)*4 + r  [m89-verified]
  const int lrbase = (wm ? 16 : 0) + quad * 4;
  if (MODE == 0 || MODE == 1) {
    unsigned short(*rp)[136] = (unsigned short(*)[136])smem;
    unsigned short* C = (unsigned short*)Cout;
#pragma unroll
    for (int mi = 0; mi < 4; ++mi) {
      __syncthreads();
#pragma unroll
      for (int ni = 0; ni < 4; ++ni)
#pragma unroll
        for (int r = 0; r < 4; ++r)
          rp[lrbase + r][wn + ni * 16 + fr] = f2bf(acc[mi][ni][r]);
      __syncthreads();
#pragma unroll
      for (int j = 0; j < 2; ++j) {
        int off = j * 2048 + t * 8;          // elem in 32x128 group
        int lr = off >> 7, c = off & 127;
        int grow = m0 + (lr >> 4) * 64 + mi * 16 + (lr & 15);
        int gcol = n0 + c;
        u16x8 v = *(const u16x8*)&rp[lr][c];
        if (MODE == 1) {
          u16x8 xv = *(const u16x8*)&xs[(size_t)grow * ldc + gcol];
          float Dh = Dvec[gcol >> 6];
          u16x8 o;
#pragma unroll
          for (int e = 0; e < 8; ++e) o[e] = f2bf(bf2f(v[e]) + Dh * bf2f(xv[e]));
          *(u16x8*)&C[(size_t)grow * ldc + gcol] = o;
        } else {
          if (gcol < Nstore) *(u16x8*)&C[(size_t)grow * ldc + gcol] = v;
        }
      }
    }
  } else {
    float(*rpf)[136] = (float(*)[136])smem;  // 32*136*4 = 17408 B
    float* C = (float*)Cout;
    if (MODE == 2) C += (size_t)blockIdx.z * DS * DI;
#pragma unroll
    for (int mi = 0; mi < 4; ++mi) {
      __syncthreads();
#pragma unroll
      for (int ni = 0; ni < 4; ++ni)
#pragma unroll
        for (int r = 0; r < 4; ++r)
          rpf[lrbase + r][wn + ni * 16 + fr] = acc[mi][ni][r];
      __syncthreads();
#pragma unroll
      for (int j = 0; j < 4; ++j) {
        int off = j * 1024 + t * 4;          // elem in 32x128 group
        int lr = off >> 7, c = off & 127;
        int grow = m0 + (lr >> 4) * 64 + mi * 16 + (lr & 15);
        int gcol = n0 + c;
        float4 v = *(const float4*)&rpf[lr][c];
        *(float4*)&C[(size_t)grow * ldc + gcol] = v;
      }
    }
  }
}

// ---------------------------------------------------------------------------
__global__ __launch_bounds__(256)
void cast_bf16_kernel(const float* __restrict__ in, unsigned short* __restrict__ out) {
  size_t i4 = ((size_t)blockIdx.x * 256 + threadIdx.x) * 4;
  float4 v = *(const float4*)(in + i4);
  u16x4 o;
  o.x = f2bf(v.x); o.y = f2bf(v.y); o.z = f2bf(v.z); o.w = f2bf(v.w);
  *(u16x4*)(out + i4) = o;
}

__global__ __launch_bounds__(256)
void cast_win_pad_kernel(const float* __restrict__ in, unsigned short* __restrict__ out) {
  size_t i4 = ((size_t)blockIdx.x * 256 + threadIdx.x) * 4;  // over 4480*1024
  int row = (int)(i4 >> 10);
  u16x4 o = (u16x4){0, 0, 0, 0};
  if (row < DPROJ) {
    float4 v = *(const float4*)(in + i4);
    o.x = f2bf(v.x); o.y = f2bf(v.y); o.z = f2bf(v.z); o.w = f2bf(v.w);
  }
  *(u16x4*)(out + i4) = o;
}

// ---------------------------------------------------------------------------
// s[l,h] = dt * exp(-dt*exp(A_log[h])),  dt = softplus(zxb[l,4352+h]+dt_bias[h])
// ---------------------------------------------------------------------------
__global__ __launch_bounds__(256)
void dt_kernel(const unsigned short* __restrict__ zxb, const float* __restrict__ dt_bias,
               const float* __restrict__ A_log, float* __restrict__ s_out) {
  int idx = blockIdx.x * 256 + threadIdx.x;  // l*32 + h
  int l = idx >> 5, h = idx & 31;
  float v = bf2f(zxb[(size_t)l * DPROJ + (DI + CDIM) + h]) + dt_bias[h];
  float d = (v > 20.f) ? v : log1pf(expf(v));
  s_out[idx] = d * expf(-d * expf(A_log[h]));
}

// ---------------------------------------------------------------------------
// conv+silu, l-tiled: block = 256 channels x 16 l's, LDS-staged 19 input rows.
// ---------------------------------------------------------------------------
__global__ __launch_bounds__(256)
void conv_silu_kernel(const unsigned short* __restrict__ zxb, const float* __restrict__ Wc,
                      const float* __restrict__ bc,
                      unsigned short* __restrict__ xs,
                      unsigned short* __restrict__ bmat,
                      unsigned short* __restrict__ cb) {
  __shared__ unsigned short zt[19][256];  // rows l0-1 .. l0+17
  const int c0 = blockIdx.x * 256;
  const int l0 = blockIdx.y * 16;
  const int t = threadIdx.x;
#pragma unroll
  for (int i = 0; i < 5; ++i) {
    int idx = i * 256 + t;                // vec4 index over 19*64
    if (idx < 19 * 64) {
      int row = idx >> 6;
      int col = (idx & 63) * 4;
      int gl = l0 - 1 + row;
      u16x4 v = (u16x4){0, 0, 0, 0};
      if (gl >= 0 && gl < L_SEQ)
        v = *(const u16x4*)&zxb[(size_t)gl * DPROJ + DI + c0 + col];
      *(u16x4*)&zt[row][col] = v;
    }
  }
  const int c = c0 + t;
  const float4 wv = *(const float4*)&Wc[c * 4];
  const float bias = bc[c];
  __syncthreads();
#pragma unroll
  for (int i = 0; i < 16; ++i) {
    int l = l0 + i;
    float s = bias + bf2f(zt[i + 0][t]) * wv.x + bf2f(zt[i + 1][t]) * wv.y +
              bf2f(zt[i + 2][t]) * wv.z + bf2f(zt[i + 3][t]) * wv.w;
    float v = s / (1.f + expf(-s));
    unsigned short b = f2bf(v);
    if (c < DI)            xs[(size_t)l * DI + c] = b;
    else if (c < DI + DS)  bmat[(size_t)l * DS + (c - DI)] = b;
    else                   cb[(size_t)l * DS + (c - DI - DS)] = b;
  }
}

// ---------------------------------------------------------------------------
// OpT[r][l]: r<2048 -> s[l,r>>6]*xs[l,r]; r in [2048,2176) -> bmat[l,r-2048]
// ---------------------------------------------------------------------------
__global__ __launch_bounds__(256)
void transpose_pack_kernel(const unsigned short* __restrict__ xs,
                           const unsigned short* __restrict__ bmat,
                           const float* __restrict__ s,
                           unsigned short* __restrict__ OpT) {
  __shared__ float tile[64][65];
  const int r0 = blockIdx.x * 64;
  const int l0 = blockIdx.y * 64;
  const int t = threadIdx.x;
  const bool isB = (r0 >= DI);
#pragma unroll
  for (int i = 0; i < 4; ++i) {
    int e = i * 1024 + t * 4;
    int lo = e >> 6;
    int ro = e & 63;
    int l = l0 + lo;
    u16x4 v;
    float sl;
    if (isB) {
      v = *(const u16x4*)&bmat[(size_t)l * DS + (r0 - DI) + ro];
      sl = 1.f;
    } else {
      v = *(const u16x4*)&xs[(size_t)l * DI + r0 + ro];
      sl = s[(size_t)l * NH + (r0 >> 6)];
    }
    tile[ro + 0][lo] = bf2f(v.x) * sl;
    tile[ro + 1][lo] = bf2f(v.y) * sl;
    tile[ro + 2][lo] = bf2f(v.z) * sl;
    tile[ro + 3][lo] = bf2f(v.w) * sl;
  }
  __syncthreads();
#pragma unroll
  for (int j = 0; j < 4; ++j) {
    int linear = j * 1024 + t * 4;
    int rr = linear >> 6;
    int lc = linear & 63;
    u16x4 o;
    o.x = f2bf(tile[rr][lc + 0]);
    o.y = f2bf(tile[rr][lc + 1]);
    o.z = f2bf(tile[rr][lc + 2]);
    o.w = f2bf(tile[rr][lc + 3]);
    *(u16x4*)&OpT[(size_t)(r0 + rr) * L_SEQ + l0 + lc] = o;
  }
}

// ---------------------------------------------------------------------------
// Ht[p][n] = bf16( sum_z Ppart[z][n][p] )
// ---------------------------------------------------------------------------
__global__ __launch_bounds__(256)
void h_reduce_t_kernel(const float* __restrict__ P, unsigned short* __restrict__ Ht) {
  __shared__ float tile[32][65];
  const int bid = blockIdx.x;
  const int pt = bid & 31, ng = bid >> 5;
  const int t = threadIdx.x;
#pragma unroll
  for (int i = 0; i < 8; ++i) {
    int nl = i * 4 + (t >> 6);
    int n = ng * 32 + nl;
    int p = pt * 64 + (t & 63);
    float acc = 0.f;
#pragma unroll
    for (int z = 0; z < KSPLIT; ++z)
      acc += P[(size_t)z * (DS * DI) + (size_t)n * DI + p];
    tile[nl][t & 63] = acc;
  }
  __syncthreads();
#pragma unroll
  for (int j = 0; j < 8; ++j) {
    int linear = j * 256 + t;
    int pl = linear >> 5, nl = linear & 31;
    Ht[(size_t)(pt * 64 + pl) * DS + ng * 32 + nl] = f2bf(tile[nl][pl]);
  }
}

// ---------------------------------------------------------------------------
// LayerNorm over 2048 (bf16 y) + z-gate (bf16 z); bf16 yz into zxb [2048,4096)
// ---------------------------------------------------------------------------
__global__ __launch_bounds__(256)
void ln_mul_kernel(const unsigned short* __restrict__ ybuf, unsigned short* __restrict__ zxb,
                   const float* __restrict__ ln_w, const float* __restrict__ ln_b) {
  int l = blockIdx.x;
  int t = threadIdx.x;
  int c0 = t * 8;
  u16x8 yv = *(const u16x8*)&ybuf[(size_t)l * DI + c0];
  float vals[8];
  float s = 0.f, sq = 0.f;
#pragma unroll
  for (int i = 0; i < 8; ++i) {
    float v = bf2f(yv[i]);
    vals[i] = v;
    s += v;
    sq += v * v;
  }
#pragma unroll
  for (int off = 32; off > 0; off >>= 1) {
    s += __shfl_down(s, off, 64);
    sq += __shfl_down(sq, off, 64);
  }
  __shared__ float red[10];
  int wave = t >> 6, lane = t & 63;
  if (lane == 0) { red[wave] = s; red[4 + wave] = sq; }
  __syncthreads();
  if (t == 0) {
    float S = red[0] + red[1] + red[2] + red[3];
    float SQ = red[4] + red[5] + red[6] + red[7];
    float mu = S / (float)DI;
    red[8] = mu;
    red[9] = rsqrtf(SQ / (float)DI - mu * mu + 1e-5f);
  }
  __syncthreads();
  float mu = red[8], rstd = red[9];
  unsigned short* zrow = zxb + (size_t)l * DPROJ;
  u16x8 zv = *(const u16x8*)&zrow[c0];
  float4 w0 = *(const float4*)&ln_w[c0], w1 = *(const float4*)&ln_w[c0 + 4];
  float4 b0 = *(const float4*)&ln_b[c0], b1 = *(const float4*)&ln_b[c0 + 4];
  float w[8] = {w0.x, w0.y, w0.z, w0.w, w1.x, w1.y, w1.z, w1.w};
  float b[8] = {b0.x, b0.y, b0.z, b0.w, b1.x, b1.y, b1.z, b1.w};
  u16x8 o;
#pragma unroll
  for (int i = 0; i < 8; ++i) {
    float v = (vals[i] - mu) * rstd * w[i] + b[i];
    o[i] = f2bf(v * bf2f(zv[i]));
  }
  *(u16x8*)&zrow[DI + c0] = o;
}

// ---------------------------------------------------------------------------
extern "C" void kernel_launch(void* const* d_in, const int* in_sizes, int n_in,
                              void* d_out, int out_size, void* d_ws, size_t ws_size,
                              hipStream_t stream) {
  const float* x       = (const float*)d_in[0];
  const float* W_in    = (const float*)d_in[1];
  const float* W_conv  = (const float*)d_in[2];
  const float* b_conv  = (const float*)d_in[3];
  const float* dt_bias = (const float*)d_in[4];
  const float* A_log   = (const float*)d_in[5];
  const float* D_param = (const float*)d_in[6];
  const float* ln_w    = (const float*)d_in[7];
  const float* ln_b    = (const float*)d_in[8];
  const float* W_out   = (const float*)d_in[9];
  float* out = (float*)d_out;

  // ---- workspace layout (~168 MB) ----
  unsigned short* zxb = (unsigned short*)d_ws;           // L*4384 bf16
  unsigned short* xs   = zxb + (size_t)L_SEQ * DPROJ;    // L*2048 bf16
  unsigned short* bmat = xs + (size_t)L_SEQ * DI;        // L*128 bf16
  unsigned short* cb   = bmat + (size_t)L_SEQ * DS;      // L*128 bf16
  float* svec = (float*)(cb + (size_t)L_SEQ * DS);       // L*32 f32
  unsigned short* OpT = (unsigned short*)(svec + (size_t)L_SEQ * NH);  // 2176*8192 bf16
  float* Ppart = (float*)(OpT + (size_t)OPROWS * L_SEQ); // 16*128*2048 f32
  unsigned short* Ht = (unsigned short*)(Ppart + (size_t)KSPLIT * DS * DI);  // 2048*128
  unsigned short* wout_bf16 = Ht + (size_t)DI * DS;      // 1024*2048 bf16
  // aliases in OpT's dead windows:
  unsigned short* x_bf16   = OpT;                        // casts..GEMM1 (16 MB)
  unsigned short* win_bf16 = OpT + (size_t)L_SEQ * DM;   // casts..GEMM1 (9.2 MB)
  unsigned short* ybuf     = OpT;                        // Y-GEMM..ln_mul (33.5 MB)

  // 0) casts
  cast_bf16_kernel<<<(L_SEQ * DM) / 1024, 256, 0, stream>>>(x, x_bf16);
  cast_win_pad_kernel<<<(NPAD_IN * DM) / 1024, 256, 0, stream>>>(W_in, win_bf16);
  cast_bf16_kernel<<<(DM * DI) / 1024, 256, 0, stream>>>(W_out, wout_bf16);

  // 1) zxb = bf16( x @ W_in^T )  (M=8192, N=4480 pad, K=1024)
  gemm_bt_mfma<0><<<dim3(NPAD_IN / 128, L_SEQ / 128), 256, 0, stream>>>(
      x_bf16, DM, win_bf16, DM, zxb, DPROJ, DM, DPROJ, nullptr, nullptr);

  // 2) s = a*dt
  dt_kernel<<<(L_SEQ * NH) / 256, 256, 0, stream>>>(zxb, dt_bias, A_log, svec);

  // 3) conv + silu (l-tiled)
  conv_silu_kernel<<<dim3(CDIM / 256, L_SEQ / 16), 256, 0, stream>>>(
      zxb, W_conv, b_conv, xs, bmat, cb);

  // 4) [Vs^T; B^T]  (clobbers x_bf16/win_bf16 — dead)
  transpose_pack_kernel<<<dim3(OPROWS / 64, L_SEQ / 64), 256, 0, stream>>>(
      xs, bmat, svec, OpT);

  // 5) Hcat = B^T @ Vs : M=128, N=2048, K=8192, split-K=16 (repacked f32 out)
  gemm_bt_mfma<2><<<dim3(DI / 128, 1, KSPLIT), 256, 0, stream>>>(
      OpT + (size_t)DI * L_SEQ, L_SEQ, OpT, L_SEQ, Ppart, DI, L_SEQ, DI,
      nullptr, nullptr);

  // 6) reduce partials + transpose -> Ht (2048 x 128 bf16)
  h_reduce_t_kernel<<<128, 256, 0, stream>>>(Ppart, Ht);

  // 7) y = C @ Hcat + D*x_ssm : M=8192, N=2048, K=128, bf16 repacked out
  gemm_bt_mfma<1><<<dim3(DI / 128, L_SEQ / 128), 256, 0, stream>>>(
      cb, DS, Ht, DS, ybuf, DI, DS, DI, xs, D_param);

  // 8) LN + z-gate -> bf16 yz into zxb cols [2048,4096)
  ln_mul_kernel<<<L_SEQ, 256, 0, stream>>>(ybuf, zxb, ln_w, ln_b);

  // 9) out = yz @ W_out^T : M=8192, N=1024, K=2048 (repacked f32 out)
  gemm_bt_mfma<3><<<dim3(DM / 128, L_SEQ / 128), 256, 0, stream>>>(
      zxb + DI, DPROJ, wout_bf16, DI, out, DM, DI, DM, nullptr, nullptr);
}

// Round 7
// 365.461 us; speedup vs baseline: 6.7050x; 1.0262x over previous
//
#include <hip/hip_runtime.h>
#include <hip/hip_bf16.h>
#include <math.h>

#define L_SEQ 8192
#define DM 1024
#define DI 2048
#define NH 32
#define HD 64
#define DS 128
#define CDIM 2304
#define DPROJ 4384
#define NPAD_IN 4480  // 35*128, zero-padded W_in rows
#define KSPLIT 32
#define OPROWS 2176   // 2048 Vs^T rows + 128 B^T rows

typedef short bf16x8 __attribute__((ext_vector_type(8)));
typedef float floatx4 __attribute__((ext_vector_type(4)));
typedef unsigned short u16x4 __attribute__((ext_vector_type(4)));
typedef unsigned short u16x8 __attribute__((ext_vector_type(8)));

#define AS1(p) ((const __attribute__((address_space(1))) void*)(p))
#define AS3(p) ((__attribute__((address_space(3))) void*)(p))

__device__ __forceinline__ float bf2f(unsigned short u) {
  union { unsigned int i; float f; } c; c.i = ((unsigned int)u) << 16; return c.f;
}
__device__ __forceinline__ unsigned short f2bf(float f) {
  return __bfloat16_as_ushort(__float2bfloat16(f));
}

// ---------------------------------------------------------------------------
// bf16 MFMA GEMM: C[m,n] = sum_k A[m,k]*B[n,k]  (K contiguous both operands)
// 128x128 tile, BK=32, 4 waves (2x2), 4x4 frags of 16x16x32 each.
// XCD-aware swizzle (modes 0/1/3, gy==64): linear id round-robins over 8 XCDs;
// map xcd=linear&7 to an 8-m-row band, m-fastest within n (r6: FETCH 219->60MB).
// All modes use LDS-repacked coalesced epilogues (no partial-line RFO):
// MODE 0: bf16 out, ushort8 sweep, 8-col-run guard (Nstore % 8 == 0).
// MODE 1: bf16 out, ushort8 sweep, fused + Dvec[gcol>>6]*bf16(xs[...]).
// MODE 2: f32 out, float4 sweep, split-K (blockIdx.z -> K-chunk & slice).
// MODE 3: f32 out, float4 sweep (grid must cover N exactly).
// ---------------------------------------------------------------------------
template <int MODE>
__global__ __launch_bounds__(256)
void gemm_bt_mfma(const unsigned short* __restrict__ A, int lda,
                  const unsigned short* __restrict__ B, int ldb,
                  void* __restrict__ Cout, int ldc,
                  int Kfull, int Nstore,
                  const unsigned short* __restrict__ xs,
                  const float* __restrict__ Dvec) {
  __shared__ __align__(16) char smem[17408];  // staging 16 KB; f32 repack 17 KB
  unsigned short* Asm = (unsigned short*)smem;
  unsigned short* Bsm = Asm + 128 * 32;
  const int t = threadIdx.x;

  int bx = blockIdx.x, by = blockIdx.y;
  if (MODE != 2) {
    int gx = gridDim.x;
    int linear = by * gx + bx;
    int xcd = linear & 7;
    int local = linear >> 3;
    by = xcd * 8 + (local & 7);
    bx = local >> 3;
  }
  const int m0 = by * 128;
  const int n0 = bx * 128;

  int kstart = 0, klen = Kfull;
  if (MODE == 2) { klen = Kfull / KSPLIT; kstart = blockIdx.z * klen; }
  const int wave = t >> 6, lane = t & 63;
  const int wm = (wave & 1) * 64;
  const int wn = (wave >> 1) * 64;
  const int fr = lane & 15;
  const int quad = lane >> 4;

  floatx4 acc[4][4];
#pragma unroll
  for (int i = 0; i < 4; ++i)
#pragma unroll
    for (int j = 0; j < 4; ++j) acc[i][j] = (floatx4){0.f, 0.f, 0.f, 0.f};

  for (int k0 = kstart; k0 < kstart + klen; k0 += 32) {
#pragma unroll
    for (int i = 0; i < 2; ++i) {
      int linear = i * 256 + t;          // 0..511
      int row = linear >> 2;             // 0..127
      int kq = (linear & 3) * 8;         // bf16 elem offset in K
      const unsigned short* ga = A + (size_t)(m0 + row) * lda + (k0 + kq);
      const unsigned short* gb = B + (size_t)(n0 + row) * ldb + (k0 + kq);
      __builtin_amdgcn_global_load_lds(AS1(ga), AS3(&Asm[linear * 8]), 16, 0, 0);
      __builtin_amdgcn_global_load_lds(AS1(gb), AS3(&Bsm[linear * 8]), 16, 0, 0);
    }
    __syncthreads();

    bf16x8 af[4], bfr[4];
#pragma unroll
    for (int i = 0; i < 4; ++i) {
      af[i]  = *(const bf16x8*)&Asm[(wm + i * 16 + fr) * 32 + quad * 8];
      bfr[i] = *(const bf16x8*)&Bsm[(wn + i * 16 + fr) * 32 + quad * 8];
    }
#pragma unroll
    for (int mi = 0; mi < 4; ++mi)
#pragma unroll
      for (int ni = 0; ni < 4; ++ni)
        acc[mi][ni] = __builtin_amdgcn_mfma_f32_16x16x32_bf16(
            af[mi], bfr[ni], acc[mi][ni], 0, 0, 0);
    __syncthreads();
  }

  // C/D frag layout: col = lane&15, row = (lane>>4)*4 + r  [m89-verified]
  const int lrbase = (wm ? 16 : 0) + quad * 4;
  if (MODE == 0 || MODE == 1) {
    unsigned short(*rp)[136] = (unsigned short(*)[136])smem;
    unsigned short* C = (unsigned short*)Cout;
#pragma unroll
    for (int mi = 0; mi < 4; ++mi) {
      __syncthreads();
#pragma unroll
      for (int ni = 0; ni < 4; ++ni)
#pragma unroll
        for (int r = 0; r < 4; ++r)
          rp[lrbase + r][wn + ni * 16 + fr] = f2bf(acc[mi][ni][r]);
      __syncthreads();
#pragma unroll
      for (int j = 0; j < 2; ++j) {
        int off = j * 2048 + t * 8;          // elem in 32x128 group
        int lr = off >> 7, c = off & 127;
        int grow = m0 + (lr >> 4) * 64 + mi * 16 + (lr & 15);
        int gcol = n0 + c;
        u16x8 v = *(const u16x8*)&rp[lr][c];
        if (MODE == 1) {
          u16x8 xv = *(const u16x8*)&xs[(size_t)grow * ldc + gcol];
          float Dh = Dvec[gcol >> 6];
          u16x8 o;
#pragma unroll
          for (int e = 0; e < 8; ++e) o[e] = f2bf(bf2f(v[e]) + Dh * bf2f(xv[e]));
          *(u16x8*)&C[(size_t)grow * ldc + gcol] = o;
        } else {
          if (gcol < Nstore) *(u16x8*)&C[(size_t)grow * ldc + gcol] = v;
        }
      }
    }
  } else {
    float(*rpf)[136] = (float(*)[136])smem;  // 32*136*4 = 17408 B
    float* C = (float*)Cout;
    if (MODE == 2) C += (size_t)blockIdx.z * DS * DI;
#pragma unroll
    for (int mi = 0; mi < 4; ++mi) {
      __syncthreads();
#pragma unroll
      for (int ni = 0; ni < 4; ++ni)
#pragma unroll
        for (int r = 0; r < 4; ++r)
          rpf[lrbase + r][wn + ni * 16 + fr] = acc[mi][ni][r];
      __syncthreads();
#pragma unroll
      for (int j = 0; j < 4; ++j) {
        int off = j * 1024 + t * 4;          // elem in 32x128 group
        int lr = off >> 7, c = off & 127;
        int grow = m0 + (lr >> 4) * 64 + mi * 16 + (lr & 15);
        int gcol = n0 + c;
        float4 v = *(const float4*)&rpf[lr][c];
        *(float4*)&C[(size_t)grow * ldc + gcol] = v;
      }
    }
  }
}

// ---------------------------------------------------------------------------
// One merged cast dispatch. Regions (in 256-thread blocks of 4-elem quads):
//   [0, 8192):        x       (8192x1024 f32 -> bf16)
//   [8192, 12672):    W_in    (4384x1024 -> 4480x1024 bf16, pad rows zero)
//   [12672, 14720):   W_out   (1024x2048 f32 -> bf16)
// ---------------------------------------------------------------------------
__global__ __launch_bounds__(256)
void cast_all_kernel(const float* __restrict__ x, const float* __restrict__ W_in,
                     const float* __restrict__ W_out,
                     unsigned short* __restrict__ x_bf16,
                     unsigned short* __restrict__ win_bf16,
                     unsigned short* __restrict__ wout_bf16) {
  int b = blockIdx.x;
  int t = threadIdx.x;
  u16x4 o = (u16x4){0, 0, 0, 0};
  if (b < 8192) {
    size_t i4 = ((size_t)b * 256 + t) * 4;
    float4 v = *(const float4*)(x + i4);
    o.x = f2bf(v.x); o.y = f2bf(v.y); o.z = f2bf(v.z); o.w = f2bf(v.w);
    *(u16x4*)(x_bf16 + i4) = o;
  } else if (b < 12672) {
    size_t i4 = ((size_t)(b - 8192) * 256 + t) * 4;  // over 4480*1024
    int row = (int)(i4 >> 10);
    if (row < DPROJ) {
      float4 v = *(const float4*)(W_in + i4);
      o.x = f2bf(v.x); o.y = f2bf(v.y); o.z = f2bf(v.z); o.w = f2bf(v.w);
    }
    *(u16x4*)(win_bf16 + i4) = o;
  } else {
    size_t i4 = ((size_t)(b - 12672) * 256 + t) * 4;
    float4 v = *(const float4*)(W_out + i4);
    o.x = f2bf(v.x); o.y = f2bf(v.y); o.z = f2bf(v.z); o.w = f2bf(v.w);
    *(u16x4*)(wout_bf16 + i4) = o;
  }
}

// ---------------------------------------------------------------------------
// s[l,h] = dt * exp(-dt*exp(A_log[h])),  dt = softplus(zxb[l,4352+h]+dt_bias[h])
// ---------------------------------------------------------------------------
__global__ __launch_bounds__(256)
void dt_kernel(const unsigned short* __restrict__ zxb, const float* __restrict__ dt_bias,
               const float* __restrict__ A_log, float* __restrict__ s_out) {
  int idx = blockIdx.x * 256 + threadIdx.x;  // l*32 + h
  int l = idx >> 5, h = idx & 31;
  float v = bf2f(zxb[(size_t)l * DPROJ + (DI + CDIM) + h]) + dt_bias[h];
  float d = (v > 20.f) ? v : log1pf(expf(v));
  s_out[idx] = d * expf(-d * expf(A_log[h]));
}

// ---------------------------------------------------------------------------
// Fused conv+silu+transpose. Block = 64 channels x 64 l, 256 threads.
// Stages 67 zxb rows; computes conv+silu; emits:
//   c<2048  : xs[l][c] = v (bf16)  and  OpT[c][l] = v*s[l][c>>6]
//   c<2176  : OpT[c][l] = v        (B rows of the packed operand)
//   else    : cb[l][c-2176] = v    (C, row-major for the Y-GEMM)
// OpT writes go through an LDS transpose tile (full-line u16x4 stores).
// ---------------------------------------------------------------------------
__global__ __launch_bounds__(256)
void conv_fused_kernel(const unsigned short* __restrict__ zxb,
                       const float* __restrict__ Wc,
                       const float* __restrict__ bc,
                       const float* __restrict__ svec,
                       unsigned short* __restrict__ xs,
                       unsigned short* __restrict__ cb,
                       unsigned short* __restrict__ OpT) {
  __shared__ unsigned short zt[67][66];
  __shared__ unsigned short ot[64][66];
  __shared__ float sl[64];
  const int c0 = blockIdx.x * 64;
  const int l0 = blockIdx.y * 64;
  const int t = threadIdx.x;
  for (int idx = t; idx < 67 * 16; idx += 256) {
    int row = idx >> 4;
    int colq = (idx & 15) * 4;
    int gl = l0 - 1 + row;
    u16x4 v = (u16x4){0, 0, 0, 0};
    if (gl >= 0 && gl < L_SEQ)
      v = *(const u16x4*)&zxb[(size_t)gl * DPROJ + DI + c0 + colq];
    *(u16x4*)&zt[row][colq] = v;
  }
  const bool isX = (c0 < DI);
  const bool isC = (c0 >= DI + DS);
  if (isX && t < 64) sl[t] = svec[(size_t)(l0 + t) * NH + (c0 >> 6)];
  const int c = t & 63;
  const int gc = c0 + c;
  const float4 wv = *(const float4*)&Wc[gc * 4];
  const float bias = bc[gc];
  const int lq = (t >> 6) * 16;
  __syncthreads();
#pragma unroll
  for (int i = 0; i < 16; ++i) {
    int ll = lq + i;
    float sacc = bias + bf2f(zt[ll][c]) * wv.x + bf2f(zt[ll + 1][c]) * wv.y +
                 bf2f(zt[ll + 2][c]) * wv.z + bf2f(zt[ll + 3][c]) * wv.w;
    float v = sacc / (1.f + expf(-sacc));
    int gl = l0 + ll;
    if (isC) {
      cb[(size_t)gl * DS + (gc - (DI + DS))] = f2bf(v);
    } else if (isX) {
      xs[(size_t)gl * DI + gc] = f2bf(v);
      ot[c][ll] = f2bf(v * sl[ll]);
    } else {
      ot[c][ll] = f2bf(v);
    }
  }
  if (!isC) {
    __syncthreads();
#pragma unroll
    for (int j = 0; j < 4; ++j) {
      int linear = j * 1024 + t * 4;
      int rr = linear >> 6;
      int lc = linear & 63;
      *(u16x4*)&OpT[(size_t)(c0 + rr) * L_SEQ + l0 + lc] = *(const u16x4*)&ot[rr][lc];
    }
  }
}

// ---------------------------------------------------------------------------
// Ht[p][n] = bf16( sum_z Ppart[z][n][p] )
// ---------------------------------------------------------------------------
__global__ __launch_bounds__(256)
void h_reduce_t_kernel(const float* __restrict__ P, unsigned short* __restrict__ Ht) {
  __shared__ float tile[32][65];
  const int bid = blockIdx.x;
  const int pt = bid & 31, ng = bid >> 5;
  const int t = threadIdx.x;
#pragma unroll
  for (int i = 0; i < 8; ++i) {
    int nl = i * 4 + (t >> 6);
    int n = ng * 32 + nl;
    int p = pt * 64 + (t & 63);
    float acc = 0.f;
#pragma unroll
    for (int z = 0; z < KSPLIT; ++z)
      acc += P[(size_t)z * (DS * DI) + (size_t)n * DI + p];
    tile[nl][t & 63] = acc;
  }
  __syncthreads();
#pragma unroll
  for (int j = 0; j < 8; ++j) {
    int linear = j * 256 + t;
    int pl = linear >> 5, nl = linear & 31;
    Ht[(size_t)(pt * 64 + pl) * DS + ng * 32 + nl] = f2bf(tile[nl][pl]);
  }
}

// ---------------------------------------------------------------------------
// LayerNorm over 2048 (bf16 y) + z-gate (bf16 z); bf16 yz into zxb [2048,4096)
// ---------------------------------------------------------------------------
__global__ __launch_bounds__(256)
void ln_mul_kernel(const unsigned short* __restrict__ ybuf, unsigned short* __restrict__ zxb,
                   const float* __restrict__ ln_w, const float* __restrict__ ln_b) {
  int l = blockIdx.x;
  int t = threadIdx.x;
  int c0 = t * 8;
  u16x8 yv = *(const u16x8*)&ybuf[(size_t)l * DI + c0];
  float vals[8];
  float s = 0.f, sq = 0.f;
#pragma unroll
  for (int i = 0; i < 8; ++i) {
    float v = bf2f(yv[i]);
    vals[i] = v;
    s += v;
    sq += v * v;
  }
#pragma unroll
  for (int off = 32; off > 0; off >>= 1) {
    s += __shfl_down(s, off, 64);
    sq += __shfl_down(sq, off, 64);
  }
  __shared__ float red[10];
  int wave = t >> 6, lane = t & 63;
  if (lane == 0) { red[wave] = s; red[4 + wave] = sq; }
  __syncthreads();
  if (t == 0) {
    float S = red[0] + red[1] + red[2] + red[3];
    float SQ = red[4] + red[5] + red[6] + red[7];
    float mu = S / (float)DI;
    red[8] = mu;
    red[9] = rsqrtf(SQ / (float)DI - mu * mu + 1e-5f);
  }
  __syncthreads();
  float mu = red[8], rstd = red[9];
  unsigned short* zrow = zxb + (size_t)l * DPROJ;
  u16x8 zv = *(const u16x8*)&zrow[c0];
  float4 w0 = *(const float4*)&ln_w[c0], w1 = *(const float4*)&ln_w[c0 + 4];
  float4 b0 = *(const float4*)&ln_b[c0], b1 = *(const float4*)&ln_b[c0 + 4];
  float w[8] = {w0.x, w0.y, w0.z, w0.w, w1.x, w1.y, w1.z, w1.w};
  float b[8] = {b0.x, b0.y, b0.z, b0.w, b1.x, b1.y, b1.z, b1.w};
  u16x8 o;
#pragma unroll
  for (int i = 0; i < 8; ++i) {
    float v = (vals[i] - mu) * rstd * w[i] + b[i];
    o[i] = f2bf(v * bf2f(zv[i]));
  }
  *(u16x8*)&zrow[DI + c0] = o;
}

// ---------------------------------------------------------------------------
extern "C" void kernel_launch(void* const* d_in, const int* in_sizes, int n_in,
                              void* d_out, int out_size, void* d_ws, size_t ws_size,
                              hipStream_t stream) {
  const float* x       = (const float*)d_in[0];
  const float* W_in    = (const float*)d_in[1];
  const float* W_conv  = (const float*)d_in[2];
  const float* b_conv  = (const float*)d_in[3];
  const float* dt_bias = (const float*)d_in[4];
  const float* A_log   = (const float*)d_in[5];
  const float* D_param = (const float*)d_in[6];
  const float* ln_w    = (const float*)d_in[7];
  const float* ln_b    = (const float*)d_in[8];
  const float* W_out   = (const float*)d_in[9];
  float* out = (float*)d_out;

  // ---- workspace layout (~183 MB) ----
  unsigned short* zxb = (unsigned short*)d_ws;           // L*4384 bf16
  unsigned short* xs   = zxb + (size_t)L_SEQ * DPROJ;    // L*2048 bf16
  unsigned short* cb   = xs + (size_t)L_SEQ * DI;        // L*128 bf16
  float* svec = (float*)(cb + (size_t)L_SEQ * DS);       // L*32 f32
  unsigned short* OpT = (unsigned short*)(svec + (size_t)L_SEQ * NH);  // 2176*8192 bf16
  float* Ppart = (float*)(OpT + (size_t)OPROWS * L_SEQ); // 32*128*2048 f32
  unsigned short* Ht = (unsigned short*)(Ppart + (size_t)KSPLIT * DS * DI);  // 2048*128
  unsigned short* wout_bf16 = Ht + (size_t)DI * DS;      // 1024*2048 bf16
  // aliases in OpT's dead windows:
  unsigned short* x_bf16   = OpT;                        // casts..GEMM1 (16 MB)
  unsigned short* win_bf16 = OpT + (size_t)L_SEQ * DM;   // casts..GEMM1 (9.2 MB)
  unsigned short* ybuf     = OpT;                        // Y-GEMM..ln_mul (33.5 MB)

  // 0) all casts in one dispatch
  cast_all_kernel<<<14720, 256, 0, stream>>>(x, W_in, W_out, x_bf16, win_bf16,
                                             wout_bf16);

  // 1) zxb = bf16( x @ W_in^T )  (M=8192, N=4480 pad, K=1024)
  gemm_bt_mfma<0><<<dim3(NPAD_IN / 128, L_SEQ / 128), 256, 0, stream>>>(
      x_bf16, DM, win_bf16, DM, zxb, DPROJ, DM, DPROJ, nullptr, nullptr);

  // 2) s = a*dt
  dt_kernel<<<(L_SEQ * NH) / 256, 256, 0, stream>>>(zxb, dt_bias, A_log, svec);

  // 3) conv + silu + transpose-pack (clobbers x_bf16/win_bf16 — dead)
  conv_fused_kernel<<<dim3(CDIM / 64, L_SEQ / 64), 256, 0, stream>>>(
      zxb, W_conv, b_conv, svec, xs, cb, OpT);

  // 4) Hcat = B^T @ Vs : M=128, N=2048, K=8192, split-K=32 (repacked f32 out)
  gemm_bt_mfma<2><<<dim3(DI / 128, 1, KSPLIT), 256, 0, stream>>>(
      OpT + (size_t)DI * L_SEQ, L_SEQ, OpT, L_SEQ, Ppart, DI, L_SEQ, DI,
      nullptr, nullptr);

  // 5) reduce partials + transpose -> Ht (2048 x 128 bf16)
  h_reduce_t_kernel<<<128, 256, 0, stream>>>(Ppart, Ht);

  // 6) y = C @ Hcat + D*x_ssm : M=8192, N=2048, K=128, bf16 repacked out
  gemm_bt_mfma<1><<<dim3(DI / 128, L_SEQ / 128), 256, 0, stream>>>(
      cb, DS, Ht, DS, ybuf, DI, DS, DI, xs, D_param);

  // 7) LN + z-gate -> bf16 yz into zxb cols [2048,4096)
  ln_mul_kernel<<<L_SEQ, 256, 0, stream>>>(ybuf, zxb, ln_w, ln_b);

  // 8) out = yz @ W_out^T : M=8192, N=1024, K=2048 (repacked f32 out)
  gemm_bt_mfma<3><<<dim3(DM / 128, L_SEQ / 128), 256, 0, stream>>>(
      zxb + DI, DPROJ, wout_bf16, DI, out, DM, DI, DM, nullptr, nullptr);
}